// Round 1
// baseline (640.202 us; speedup 1.0000x reference)
//
#include <hip/hip_runtime.h>
#include <math.h>

#define NN 100000
#define EE 1600000
#define GG 512
#define INF_ 128
#define HID 64
#define EPS 1e-5f

#define NBUK 391          // ceil(NN/256), bucket = dst >> 8
#define P1_TILES 98       // ceil((EE/4)/4096)
#define SETUP_B 25        // ceil(6208/256)
#define POOL_WORDS (GG * 64 * 2 + GG)
#define ZERO_B ((POOL_WORDS + 255) / 256)

typedef unsigned int uint32;
typedef __attribute__((ext_vector_type(8))) short bf16x8;
typedef __attribute__((ext_vector_type(4))) float f32x4;

// bf16 helpers: RNE pack, shift decode
static __device__ inline uint32 f2bf(float f) {
    uint32 u = __float_as_uint(f);
    return (u + 0x7FFFu + ((u >> 16) & 1u)) >> 16;
}
static __device__ inline float bf_lo(uint32 u) { return __uint_as_float(u << 16); }
static __device__ inline float bf_hi(uint32 u) { return __uint_as_float(u & 0xFFFF0000u); }

// ---------------- CSR build: 2-level counting sort, single-histogram ------
// R3: per-edge atomic scatter -> 12x cross-XCD write amplification; bucketed.
// R7: chunk-split gather quadruplicated per-edge overhead -> reverted.
// R9: hist computed ONCE into per-block hblk; scan2 derives per-(block,bucket)
// run bases deterministically; p1b only scatters. Setup + pool-zero fused.
// R10 (this round): gather is latency-bound (VALU 48%, HBM 36%, nothing
// saturated). hwb rows pre-scaled by dinv[src] in GEMM epilogue (kills the
// per-edge dinv gather + weight); edge lists read via wave-uniform scalar
// loads (kills 2 ds_bpermute/edge + index VALU).

// blocks [0,98): per-block dst histogram -> hblk. [98,123): setup. rest: zero pool.
__global__ __launch_bounds__(256) void k_hist1(const int* __restrict__ ei,
        int* __restrict__ hblk,
        const float* b1, const float* g1, const float* be1,
        const float* rm1, const float* rv1,
        const float* b2, const float* g2, const float* be2,
        const float* rm2, const float* rv2, float* sc,
        const float* W1, uint32* Wt1b, const float* W2, uint32* Wt2b,
        float* poolz) {
    int b = blockIdx.x, t = threadIdx.x;
    if (b < P1_TILES) {
        __shared__ int h[NBUK];
        for (int i = t; i < NBUK; i += 256) h[i] = 0;
        __syncthreads();
        const int4* dst4 = (const int4*)(ei + EE);
        int base4 = b * 4096;
        for (int j = 0; j < 16; ++j) {
            int i4 = base4 + j * 256 + t;
            if (i4 < EE / 4) {
                int4 d = dst4[i4];
                atomicAdd(&h[d.x >> 8], 1);
                atomicAdd(&h[d.y >> 8], 1);
                atomicAdd(&h[d.z >> 8], 1);
                atomicAdd(&h[d.w >> 8], 1);
            }
        }
        __syncthreads();
        for (int i = t; i < NBUK; i += 256) hblk[b * NBUK + i] = h[i];
    } else if (b < P1_TILES + SETUP_B) {
        int i = (b - P1_TILES) * 256 + t;
        if (i < 4096) {                       // Wt1b: K=128
            int n = i >> 6, kp = (i & 63) * 2;
            Wt1b[i] = f2bf(W1[(size_t)kp * 64 + n]) |
                      (f2bf(W1[(size_t)(kp + 1) * 64 + n]) << 16);
        } else if (i < 6144) {                // Wt2b: K=64
            int j = i - 4096;
            int n = j >> 5, kp = (j & 31) * 2;
            Wt2b[j] = f2bf(W2[(size_t)kp * 64 + n]) |
                      (f2bf(W2[(size_t)(kp + 1) * 64 + n]) << 16);
        } else if (i < 6208) {                // BN fold
            int l = i - 6144;
            float s1 = g1[l] * rsqrtf(rv1[l] + EPS);
            sc[l]       = s1;
            sc[64 + l]  = (b1[l] - rm1[l]) * s1 + be1[l];
            float s2 = g2[l] * rsqrtf(rv2[l] + EPS);
            sc[128 + l] = s2;
            sc[192 + l] = (b2[l] - rm2[l]) * s2 + be2[l];
        }
    } else {
        int i = (b - P1_TILES - SETUP_B) * 256 + t;
        if (i < POOL_WORDS) poolz[i] = 0.f;
    }
}

// one block, 512 threads: bucket totals, bucket scan -> bbase, per-block run
// bases -> rbase[98][NBUK]. All deterministic, no atomics.
// R10: also zeroes the 16-int col[] pad (safe unguarded chunk reads in gather).
__global__ void k_scan2(const int* __restrict__ hblk, int* __restrict__ bbase,
                        int* __restrict__ rbase, int* __restrict__ offs,
                        int* __restrict__ col) {
    __shared__ int wsum[8];
    int t = threadIdx.x;  // 512
    int lane = t & 63, w = t >> 6;
    if (t < 16) col[EE + t] = 0;
    int c = 0;
    if (t < NBUK)
        for (int b = 0; b < P1_TILES; ++b) c += hblk[b * NBUK + t];
    int v = c;
    for (int d = 1; d < 64; d <<= 1) { int n = __shfl_up(v, d); if (lane >= d) v += n; }
    if (lane == 63) wsum[w] = v;
    __syncthreads();
    int pre = 0;
    for (int q = 0; q < w; ++q) pre += wsum[q];
    int excl = pre + v - c;
    if (t <= NBUK) bbase[t] = excl;
    if (t == 0) offs[NN] = EE;
    if (t < NBUK) {
        int run = excl;
        for (int b = 0; b < P1_TILES; ++b) {
            rbase[b * NBUK + t] = run;
            run += hblk[b * NBUK + t];
        }
    }
}

// scatter packed (src<<8)|(dst&255) into CSR-ordered bucket regions
__global__ __launch_bounds__(256) void k_p1b(const int* __restrict__ ei,
                                             const int* __restrict__ rbase,
                                             uint32* __restrict__ pairs) {
    __shared__ int h[NBUK];
    int b = blockIdx.x, t = threadIdx.x;
    for (int i = t; i < NBUK; i += 256) h[i] = rbase[b * NBUK + i];
    __syncthreads();
    const int4* src4 = (const int4*)ei;
    const int4* dst4 = (const int4*)(ei + EE);
    int base4 = b * 4096;
    for (int j = 0; j < 16; ++j) {
        int i4 = base4 + j * 256 + t;
        if (i4 < EE / 4) {
            int4 d = dst4[i4];
            int4 s = src4[i4];
            int p0 = atomicAdd(&h[d.x >> 8], 1);
            pairs[p0] = ((uint32)s.x << 8) | (uint32)(d.x & 255);
            int p1 = atomicAdd(&h[d.y >> 8], 1);
            pairs[p1] = ((uint32)s.y << 8) | (uint32)(d.y & 255);
            int p2 = atomicAdd(&h[d.z >> 8], 1);
            pairs[p2] = ((uint32)s.z << 8) | (uint32)(d.z & 255);
            int p3 = atomicAdd(&h[d.w >> 8], 1);
            pairs[p3] = ((uint32)s.w << 8) | (uint32)(d.w & 255);
        }
    }
}

// per-bucket (256 nodes) CSR finalize in LDS: count, scan, scatter col
__global__ __launch_bounds__(256) void k_p2(const uint32* __restrict__ pairs,
                                            const int* __restrict__ bbase,
                                            int* __restrict__ offs, float* __restrict__ dinv,
                                            int* __restrict__ col) {
    int b = blockIdx.x, t = threadIdx.x;
    int nbase = b << 8;
    int ebase = bbase[b], eend = bbase[b + 1];
    int m = eend - ebase;
    __shared__ int cnt[256];
    __shared__ int wsum[4];
    cnt[t] = 0;
    __syncthreads();
    for (int i = t; i < m; i += 256)
        atomicAdd(&cnt[pairs[ebase + i] & 255u], 1);
    __syncthreads();
    int c = cnt[t];
    int lane = t & 63, w = t >> 6;
    int v = c;
    for (int d = 1; d < 64; d <<= 1) { int n = __shfl_up(v, d); if (lane >= d) v += n; }
    if (lane == 63) wsum[w] = v;
    __syncthreads();
    int pre = 0;
    for (int q = 0; q < w; ++q) pre += wsum[q];
    int excl = pre + v - c;
    int node = nbase + t;
    if (node < NN) {
        offs[node] = ebase + excl;
        dinv[node] = rsqrtf(1.f + (float)c);
    }
    __syncthreads();
    cnt[t] = excl;
    __syncthreads();
    for (int i = t; i < m; i += 256) {
        uint32 u = pairs[ebase + i];
        int loc = atomicAdd(&cnt[u & 255u], 1);
        col[ebase + loc] = (int)(u >> 8);
    }
}

// ---------------- MFMA GEMM: [nrows,K]f32 @ [K,64]bf16 -> bf16 packed -----
// 64x64 tile/block, 4 waves x 4 n-tiles x K/32 k-steps, 16x16x32 bf16 MFMA.
// Rows padded +8 bf16: 256B-stride frag loads 16-way -> 2-way (free, m136).
// R10: epilogue scales row by dinv[row] so gather needs no per-edge weight.
template <int K>
__global__ __launch_bounds__(256) void k_gemm_mfma(const float* __restrict__ X,
                                                   const uint32* __restrict__ Wtb,
                                                   const float* __restrict__ dinv,
                                                   uint32* __restrict__ outb, int nrows) {
    constexpr int KP = K + 8;
    __shared__ alignas(16) unsigned short Al[64 * KP];
    __shared__ alignas(16) unsigned short Bl[64 * KP];
    int tid = threadIdx.x;
    for (int i = tid; i < 64 * (K / 2); i += 256) {
        int n = i / (K / 2), kp = i % (K / 2);
        *(uint32*)&Bl[n * KP + kp * 2] = Wtb[i];
    }
    int r0 = blockIdx.x * 64;
    const float* Xb = X + (size_t)r0 * K;
    int limit = (nrows - r0) * K;
    for (int f = tid * 4; f < 64 * K; f += 1024) {
        float4 v = {0.f, 0.f, 0.f, 0.f};
        if (f + 3 < limit) v = *(const float4*)&Xb[f];
        int row = f / K, kpos = f % K;
        ushort4 pk;
        pk.x = (unsigned short)f2bf(v.x);
        pk.y = (unsigned short)f2bf(v.y);
        pk.z = (unsigned short)f2bf(v.z);
        pk.w = (unsigned short)f2bf(v.w);
        *(ushort4*)&Al[row * KP + kpos] = pk;
    }
    __syncthreads();
    int lane = tid & 63, wv = tid >> 6;
    int m = lane & 15, quad = lane >> 4;
    f32x4 acc0 = {0.f, 0.f, 0.f, 0.f}, acc1 = acc0, acc2 = acc0, acc3 = acc0;
    int arow = wv * 16 + m;
#pragma unroll
    for (int k0 = 0; k0 < K; k0 += 32) {
        int koff = k0 + quad * 8;
        bf16x8 a = *(const bf16x8*)&Al[arow * KP + koff];
        bf16x8 b0 = *(const bf16x8*)&Bl[(0 * 16 + m) * KP + koff];
        bf16x8 b1 = *(const bf16x8*)&Bl[(1 * 16 + m) * KP + koff];
        bf16x8 b2 = *(const bf16x8*)&Bl[(2 * 16 + m) * KP + koff];
        bf16x8 b3 = *(const bf16x8*)&Bl[(3 * 16 + m) * KP + koff];
        acc0 = __builtin_amdgcn_mfma_f32_16x16x32_bf16(a, b0, acc0, 0, 0, 0);
        acc1 = __builtin_amdgcn_mfma_f32_16x16x32_bf16(a, b1, acc1, 0, 0, 0);
        acc2 = __builtin_amdgcn_mfma_f32_16x16x32_bf16(a, b2, acc2, 0, 0, 0);
        acc3 = __builtin_amdgcn_mfma_f32_16x16x32_bf16(a, b3, acc3, 0, 0, 0);
    }
    // C/D layout: col = nt*16 + m, row = quad*4 + reg.
    float dv[4];
#pragma unroll
    for (int reg = 0; reg < 4; ++reg) {
        int row = r0 + wv * 16 + quad * 4 + reg;
        dv[reg] = (row < nrows) ? dinv[row] : 0.f;
    }
    const float* accs[4] = {(const float*)&acc0, (const float*)&acc1,
                            (const float*)&acc2, (const float*)&acc3};
#pragma unroll
    for (int nt = 0; nt < 4; ++nt) {
#pragma unroll
        for (int reg = 0; reg < 4; ++reg) {
            float val = accs[nt][reg] * dv[reg];
            float nxt = __shfl_down(val, 1);
            int row = r0 + wv * 16 + quad * 4 + reg;
            if (((m & 1) == 0) && row < nrows)
                outb[(size_t)row * 32 + nt * 8 + (m >> 1)] =
                    f2bf(val) | (f2bf(nxt) << 16);
        }
    }
}

// ---------- fused GCN aggregate + selfloop + BN + ReLU (+resid), bf16 ------
// One wave per node; 32 lanes cover a 128B bf16 row, 2 wave halves = 2 edges
// per load. R10: hwb rows are PRE-SCALED by dinv[src] (GEMM epilogue), so the
// aggregate is an unweighted sum. Edge ids come in through the SCALAR pipe
// (node is wave-uniform -> offs/col reads are s_loads); per-pair half-select
// is one v_cndmask. Removes 2 ds_bpermute + ~8 VALU per edge and one
// dependent memory hop (dinv gather) from the node critical path.
// col[] has a zeroed 16-int pad so full-chunk reads past e1 are always safe;
// tail contributions are masked with exact 0/1 fma weights.
__global__ void k_gcn_gather(const uint32* __restrict__ hwb, const int* __restrict__ col,
                             const int* __restrict__ offs,
                             const float* __restrict__ dinv, const float* __restrict__ scale,
                             const float* __restrict__ shift, const float* resid,
                             float* out) {
    int wid = __builtin_amdgcn_readfirstlane((int)(threadIdx.x >> 6));
    int node = blockIdx.x * 4 + wid;
    if (node >= NN) return;
    int lane = (int)(threadIdx.x & 63);
    int half = lane >> 5;
    int fl = lane & 31;                 // feature pair: {2fl, 2fl+1}
    int e0 = offs[node], e1 = offs[node + 1];
    float di = dinv[node];
    uint32 uself = hwb[(uint32)node * 32u + (uint32)fl];   // hoisted: independent of edges
    float ax0 = 0.f, ay0 = 0.f, ax1 = 0.f, ay1 = 0.f;
    for (int base = e0; base < e1; base += 16) {
        const int* cp = col + base;     // wave-uniform -> scalar loads
        int m = e1 - base;              // uniform
        int s[16];
#pragma unroll
        for (int j = 0; j < 16; ++j) s[j] = cp[j];
        if (m >= 16) {
            uint32 u[8];
#pragma unroll
            for (int p = 0; p < 8; ++p) {
                int sv = half ? s[2 * p + 1] : s[2 * p];
                u[p] = hwb[(uint32)sv * 32u + (uint32)fl];
            }
#pragma unroll
            for (int p = 0; p < 8; ++p) {
                if (p & 1) { ax1 += bf_lo(u[p]); ay1 += bf_hi(u[p]); }
                else       { ax0 += bf_lo(u[p]); ay0 += bf_hi(u[p]); }
            }
        } else {
#pragma unroll
            for (int p = 0; p < 8; ++p) {
                if (2 * p < m) {        // uniform branch
                    int sv = half ? s[2 * p + 1] : s[2 * p];
                    float w = (2 * p + half < m) ? 1.f : 0.f;
                    uint32 u = hwb[(uint32)sv * 32u + (uint32)fl];
                    ax0 = fmaf(bf_lo(u), w, ax0);
                    ay0 = fmaf(bf_hi(u), w, ay0);
                }
            }
        }
    }
    float ax = ax0 + ax1, ay = ay0 + ay1;
    ax += __shfl(ax, fl + 32);
    ay += __shfl(ay, fl + 32);
    if (half == 0) {
        // rows pre-scaled: out = (sum + self_scaled) * dinv[node], then BN.
        float vx = fmaf((ax + bf_lo(uself)) * di, scale[2 * fl],     shift[2 * fl]);
        float vy = fmaf((ay + bf_hi(uself)) * di, scale[2 * fl + 1], shift[2 * fl + 1]);
        vx = fmaxf(vx, 0.f);
        vy = fmaxf(vy, 0.f);
        if (resid) {
            float2 rv = *(const float2*)&resid[(size_t)node * 64 + 2 * fl];
            vx += rv.x; vy += rv.y;
        }
        float2 o; o.x = vx; o.y = vy;
        *(float2*)&out[(size_t)node * 64 + 2 * fl] = o;
    }
}

// ---------------- pooling over sorted batch, 4 waves x 32 nodes -----------
__global__ __launch_bounds__(256) void k_pool(const float* __restrict__ h,
                       const int* __restrict__ batch,
                       float* __restrict__ msum, float* __restrict__ mmax,
                       float* __restrict__ gcnt) {
    int lane = threadIdx.x & 63;
    int wv = threadIdx.x >> 6;
    int i0 = blockIdx.x * 128 + wv * 32;
    if (i0 >= NN) return;
    int i1 = i0 + 32; if (i1 > NN) i1 = NN;
    int cur = batch[i0];
    float sum = 0.f, mx = 0.f; int c = 0;
    for (int i = i0; i < i1; ++i) {
        int g = batch[i];
        if (g != cur) {
            atomicAdd(&msum[cur * 64 + lane], sum);
            atomicMax((unsigned int*)&mmax[cur * 64 + lane], __float_as_uint(mx));
            if (lane == 0) atomicAdd(&gcnt[cur], (float)c);
            sum = 0.f; mx = 0.f; c = 0; cur = g;
        }
        float v = h[(long)i * 64 + lane];
        sum += v; mx = fmaxf(mx, v); ++c;
    }
    atomicAdd(&msum[cur * 64 + lane], sum);
    atomicMax((unsigned int*)&mmax[cur * 64 + lane], __float_as_uint(mx));
    if (lane == 0) atomicAdd(&gcnt[cur], (float)c);
}

// ---------------- MLP head, one block per graph ----------------
__global__ void k_head(const float* __restrict__ msum, const float* __restrict__ mmax,
                       const float* __restrict__ gcnt,
                       const float* __restrict__ Wh1, const float* __restrict__ bh1,
                       const float* __restrict__ Wh2, const float* __restrict__ bh2,
                       const float* __restrict__ Wh3, const float* __restrict__ bh3,
                       float* __restrict__ out) {
    int g = blockIdx.x, t = threadIdx.x;  // 64 threads
    __shared__ float hg[128];
    __shared__ float z1[64];
    __shared__ float z2[32];
    float c = fmaxf(gcnt[g], 1.f);
    hg[t]      = msum[g * 64 + t] / c;
    hg[64 + t] = mmax[g * 64 + t];
    __syncthreads();
    float acc = bh1[t];
#pragma unroll 8
    for (int k = 0; k < 128; ++k) acc = fmaf(hg[k], Wh1[k * 64 + t], acc);
    z1[t] = fmaxf(acc, 0.f);
    __syncthreads();
    if (t < 32) {
        float a2 = bh2[t];
#pragma unroll 8
        for (int k = 0; k < 64; ++k) a2 = fmaf(z1[k], Wh2[k * 32 + t], a2);
        z2[t] = fmaxf(a2, 0.f);
    }
    __syncthreads();
    if (t == 0) {
        float a3 = bh3[0];
        for (int k = 0; k < 32; ++k) a3 = fmaf(z2[k], Wh3[k], a3);
        out[g] = 1.f / (1.f + expf(-a3));
    }
}

// ---------------- launcher ----------------

static inline size_t alignup(size_t x) { return (x + 255) & ~(size_t)255; }

extern "C" void kernel_launch(void* const* d_in, const int* in_sizes, int n_in,
                              void* d_out, int out_size, void* d_ws, size_t ws_size,
                              hipStream_t stream) {
    const float* x   = (const float*)d_in[0];
    const int*   ei  = (const int*)d_in[1];
    const int*   bat = (const int*)d_in[2];
    const float* W1  = (const float*)d_in[3];
    const float* b1  = (const float*)d_in[4];
    const float* g1  = (const float*)d_in[5];
    const float* be1 = (const float*)d_in[6];
    const float* rm1 = (const float*)d_in[7];
    const float* rv1 = (const float*)d_in[8];
    const float* W2  = (const float*)d_in[9];
    const float* b2  = (const float*)d_in[10];
    const float* g2  = (const float*)d_in[11];
    const float* be2 = (const float*)d_in[12];
    const float* rm2 = (const float*)d_in[13];
    const float* rv2 = (const float*)d_in[14];
    const float* Wh1 = (const float*)d_in[15];
    const float* bh1 = (const float*)d_in[16];
    const float* Wh2 = (const float*)d_in[17];
    const float* bh2 = (const float*)d_in[18];
    const float* Wh3 = (const float*)d_in[19];
    const float* bh3 = (const float*)d_in[20];
    float* out = (float*)d_out;

    char* ws = (char*)d_ws;
    size_t o = 0;
    int*   hblk   = (int*)(ws + o);  o = alignup(o + (size_t)P1_TILES * NBUK * 4);
    int*   rbase  = (int*)(ws + o);  o = alignup(o + (size_t)P1_TILES * NBUK * 4);
    int*   bbase  = (int*)(ws + o);  o = alignup(o + (NBUK + 1) * 4);
    int*   offs   = (int*)(ws + o);  o = alignup(o + (NN + 1) * 4);
    uint32* pairs = (uint32*)(ws + o); o = alignup(o + (size_t)EE * 4);
    int*   col    = (int*)(ws + o);  o = alignup(o + (size_t)(EE + 16) * 4);  // +16 pad (zeroed)
    float* dinv   = (float*)(ws + o); o = alignup(o + (size_t)NN * 4);
    float* scb    = (float*)(ws + o); o = alignup(o + 4 * 64 * 4);
    uint32* Wt1b  = (uint32*)(ws + o); o = alignup(o + 64 * (INF_ / 2) * 4);
    uint32* Wt2b  = (uint32*)(ws + o); o = alignup(o + 64 * (HID / 2) * 4);
    float* msum   = (float*)(ws + o); o += (size_t)GG * 64 * 4;
    float* mmax   = (float*)(ws + o); o += (size_t)GG * 64 * 4;
    float* gcnt   = (float*)(ws + o); o += (size_t)GG * 4;
    o = alignup(o);
    uint32* hwb   = (uint32*)(ws + o); o = alignup(o + (size_t)NN * 32 * 4);
    float* h      = (float*)(ws + o); o = alignup(o + (size_t)NN * 64 * 4);
    (void)ws_size; (void)n_in; (void)in_sizes; (void)out_size;

    // CSR build + setup + pool-zero (one kernel, 3 block roles)
    k_hist1<<<P1_TILES + SETUP_B + ZERO_B, 256, 0, stream>>>(
        ei, hblk, b1, g1, be1, rm1, rv1, b2, g2, be2, rm2, rv2, scb,
        W1, Wt1b, W2, Wt2b, msum);
    k_scan2<<<1, 512, 0, stream>>>(hblk, bbase, rbase, offs, col);
    k_p1b<<<P1_TILES, 256, 0, stream>>>(ei, rbase, pairs);
    k_p2<<<NBUK, 256, 0, stream>>>(pairs, bbase, offs, dinv, col);

    // layer 1 (GEMM epilogue pre-scales rows by dinv -> gather is a plain sum)
    k_gemm_mfma<INF_><<<(NN + 63) / 64, 256, 0, stream>>>(x, Wt1b, dinv, hwb, NN);
    k_gcn_gather<<<(NN + 3) / 4, 256, 0, stream>>>(hwb, col, offs, dinv,
                                                   scb, scb + 64, nullptr, h);
    // layer 2 (residual, in-place into h)
    k_gemm_mfma<HID><<<(NN + 63) / 64, 256, 0, stream>>>(h, Wt2b, dinv, hwb, NN);
    k_gcn_gather<<<(NN + 3) / 4, 256, 0, stream>>>(hwb, col, offs, dinv,
                                                   scb + 128, scb + 192, h, h);
    // pooling + head
    k_pool<<<(NN + 127) / 128, 256, 0, stream>>>(h, bat, msum, mmax, gcnt);
    k_head<<<GG, 64, 0, stream>>>(msum, mmax, gcnt, Wh1, bh1, Wh2, bh2, Wh3, bh3, out);
}

// Round 2
// 305.818 us; speedup vs baseline: 2.0934x; 2.0934x over previous
//
#include <hip/hip_runtime.h>
#include <math.h>

#define NN 100000
#define EE 1600000
#define GG 512
#define INF_ 128
#define HID 64
#define EPS 1e-5f

#define NBUK 391          // ceil(NN/256), bucket = dst >> 8
#define P1_TILES 98       // ceil((EE/4)/4096)
#define SETUP_B 25        // ceil(6208/256)
#define POOL_WORDS (GG * 64 * 2 + GG)
#define ZERO_B ((POOL_WORDS + 255) / 256)

typedef unsigned int uint32;
typedef __attribute__((ext_vector_type(8))) short bf16x8;
typedef __attribute__((ext_vector_type(4))) float f32x4;

// bf16 helpers: RNE pack, shift decode
static __device__ inline uint32 f2bf(float f) {
    uint32 u = __float_as_uint(f);
    return (u + 0x7FFFu + ((u >> 16) & 1u)) >> 16;
}
static __device__ inline float bf_lo(uint32 u) { return __uint_as_float(u << 16); }
static __device__ inline float bf_hi(uint32 u) { return __uint_as_float(u & 0xFFFF0000u); }

// ---------------- CSR build: 2-level counting sort, single-histogram ------
// R3: per-edge atomic scatter -> 12x cross-XCD write amplification; bucketed.
// R7: chunk-split gather quadruplicated per-edge overhead -> reverted.
// R9: hist computed ONCE into per-block hblk; scan2 derives per-(block,bucket)
// run bases deterministically; p1b only scatters. Setup + pool-zero fused.
// R10 FAILED: per-thread int s[16] in gather -> PromoteAlloca put it in LDS
// (LDS_Block_Size 0->64KB, 38M bank conflicts, occupancy 69->19%, 45->216us).
// Lesson: no indexed per-thread arrays in the gather, ever.
// R11: keep R10's verified algebra (hwb rows pre-scaled by dinv in GEMM
// epilogue -> no per-edge weight), revert gather to R9 shuffle-broadcast
// structure. Tail masked via zeroed hwb row NN instead of w=0 weights.

// blocks [0,98): per-block dst histogram -> hblk. [98,123): setup. rest: zero pool.
__global__ __launch_bounds__(256) void k_hist1(const int* __restrict__ ei,
        int* __restrict__ hblk,
        const float* b1, const float* g1, const float* be1,
        const float* rm1, const float* rv1,
        const float* b2, const float* g2, const float* be2,
        const float* rm2, const float* rv2, float* sc,
        const float* W1, uint32* Wt1b, const float* W2, uint32* Wt2b,
        float* poolz) {
    int b = blockIdx.x, t = threadIdx.x;
    if (b < P1_TILES) {
        __shared__ int h[NBUK];
        for (int i = t; i < NBUK; i += 256) h[i] = 0;
        __syncthreads();
        const int4* dst4 = (const int4*)(ei + EE);
        int base4 = b * 4096;
        for (int j = 0; j < 16; ++j) {
            int i4 = base4 + j * 256 + t;
            if (i4 < EE / 4) {
                int4 d = dst4[i4];
                atomicAdd(&h[d.x >> 8], 1);
                atomicAdd(&h[d.y >> 8], 1);
                atomicAdd(&h[d.z >> 8], 1);
                atomicAdd(&h[d.w >> 8], 1);
            }
        }
        __syncthreads();
        for (int i = t; i < NBUK; i += 256) hblk[b * NBUK + i] = h[i];
    } else if (b < P1_TILES + SETUP_B) {
        int i = (b - P1_TILES) * 256 + t;
        if (i < 4096) {                       // Wt1b: K=128
            int n = i >> 6, kp = (i & 63) * 2;
            Wt1b[i] = f2bf(W1[(size_t)kp * 64 + n]) |
                      (f2bf(W1[(size_t)(kp + 1) * 64 + n]) << 16);
        } else if (i < 6144) {                // Wt2b: K=64
            int j = i - 4096;
            int n = j >> 5, kp = (j & 31) * 2;
            Wt2b[j] = f2bf(W2[(size_t)kp * 64 + n]) |
                      (f2bf(W2[(size_t)(kp + 1) * 64 + n]) << 16);
        } else if (i < 6208) {                // BN fold
            int l = i - 6144;
            float s1 = g1[l] * rsqrtf(rv1[l] + EPS);
            sc[l]       = s1;
            sc[64 + l]  = (b1[l] - rm1[l]) * s1 + be1[l];
            float s2 = g2[l] * rsqrtf(rv2[l] + EPS);
            sc[128 + l] = s2;
            sc[192 + l] = (b2[l] - rm2[l]) * s2 + be2[l];
        }
    } else {
        int i = (b - P1_TILES - SETUP_B) * 256 + t;
        if (i < POOL_WORDS) poolz[i] = 0.f;
    }
}

// one block, 512 threads: bucket totals, bucket scan -> bbase, per-block run
// bases -> rbase[98][NBUK]. All deterministic, no atomics.
// R11: also zeroes hwb row NN (the tail-mask zero row for the gather).
__global__ void k_scan2(const int* __restrict__ hblk, int* __restrict__ bbase,
                        int* __restrict__ rbase, int* __restrict__ offs,
                        uint32* __restrict__ hwb) {
    __shared__ int wsum[8];
    int t = threadIdx.x;  // 512
    int lane = t & 63, w = t >> 6;
    if (t < 32) hwb[(size_t)NN * 32 + t] = 0u;
    int c = 0;
    if (t < NBUK)
        for (int b = 0; b < P1_TILES; ++b) c += hblk[b * NBUK + t];
    int v = c;
    for (int d = 1; d < 64; d <<= 1) { int n = __shfl_up(v, d); if (lane >= d) v += n; }
    if (lane == 63) wsum[w] = v;
    __syncthreads();
    int pre = 0;
    for (int q = 0; q < w; ++q) pre += wsum[q];
    int excl = pre + v - c;
    if (t <= NBUK) bbase[t] = excl;
    if (t == 0) offs[NN] = EE;
    if (t < NBUK) {
        int run = excl;
        for (int b = 0; b < P1_TILES; ++b) {
            rbase[b * NBUK + t] = run;
            run += hblk[b * NBUK + t];
        }
    }
}

// scatter packed (src<<8)|(dst&255) into CSR-ordered bucket regions
__global__ __launch_bounds__(256) void k_p1b(const int* __restrict__ ei,
                                             const int* __restrict__ rbase,
                                             uint32* __restrict__ pairs) {
    __shared__ int h[NBUK];
    int b = blockIdx.x, t = threadIdx.x;
    for (int i = t; i < NBUK; i += 256) h[i] = rbase[b * NBUK + i];
    __syncthreads();
    const int4* src4 = (const int4*)ei;
    const int4* dst4 = (const int4*)(ei + EE);
    int base4 = b * 4096;
    for (int j = 0; j < 16; ++j) {
        int i4 = base4 + j * 256 + t;
        if (i4 < EE / 4) {
            int4 d = dst4[i4];
            int4 s = src4[i4];
            int p0 = atomicAdd(&h[d.x >> 8], 1);
            pairs[p0] = ((uint32)s.x << 8) | (uint32)(d.x & 255);
            int p1 = atomicAdd(&h[d.y >> 8], 1);
            pairs[p1] = ((uint32)s.y << 8) | (uint32)(d.y & 255);
            int p2 = atomicAdd(&h[d.z >> 8], 1);
            pairs[p2] = ((uint32)s.z << 8) | (uint32)(d.z & 255);
            int p3 = atomicAdd(&h[d.w >> 8], 1);
            pairs[p3] = ((uint32)s.w << 8) | (uint32)(d.w & 255);
        }
    }
}

// per-bucket (256 nodes) CSR finalize in LDS: count, scan, scatter col
__global__ __launch_bounds__(256) void k_p2(const uint32* __restrict__ pairs,
                                            const int* __restrict__ bbase,
                                            int* __restrict__ offs, float* __restrict__ dinv,
                                            int* __restrict__ col) {
    int b = blockIdx.x, t = threadIdx.x;
    int nbase = b << 8;
    int ebase = bbase[b], eend = bbase[b + 1];
    int m = eend - ebase;
    __shared__ int cnt[256];
    __shared__ int wsum[4];
    cnt[t] = 0;
    __syncthreads();
    for (int i = t; i < m; i += 256)
        atomicAdd(&cnt[pairs[ebase + i] & 255u], 1);
    __syncthreads();
    int c = cnt[t];
    int lane = t & 63, w = t >> 6;
    int v = c;
    for (int d = 1; d < 64; d <<= 1) { int n = __shfl_up(v, d); if (lane >= d) v += n; }
    if (lane == 63) wsum[w] = v;
    __syncthreads();
    int pre = 0;
    for (int q = 0; q < w; ++q) pre += wsum[q];
    int excl = pre + v - c;
    int node = nbase + t;
    if (node < NN) {
        offs[node] = ebase + excl;
        dinv[node] = rsqrtf(1.f + (float)c);
    }
    __syncthreads();
    cnt[t] = excl;
    __syncthreads();
    for (int i = t; i < m; i += 256) {
        uint32 u = pairs[ebase + i];
        int loc = atomicAdd(&cnt[u & 255u], 1);
        col[ebase + loc] = (int)(u >> 8);
    }
}

// ---------------- MFMA GEMM: [nrows,K]f32 @ [K,64]bf16 -> bf16 packed -----
// 64x64 tile/block, 4 waves x 4 n-tiles x K/32 k-steps, 16x16x32 bf16 MFMA.
// Rows padded +8 bf16: 256B-stride frag loads 16-way -> 2-way (free, m136).
// R10 (verified): epilogue scales row by dinv[row] so gather is unweighted.
template <int K>
__global__ __launch_bounds__(256) void k_gemm_mfma(const float* __restrict__ X,
                                                   const uint32* __restrict__ Wtb,
                                                   const float* __restrict__ dinv,
                                                   uint32* __restrict__ outb, int nrows) {
    constexpr int KP = K + 8;
    __shared__ alignas(16) unsigned short Al[64 * KP];
    __shared__ alignas(16) unsigned short Bl[64 * KP];
    int tid = threadIdx.x;
    for (int i = tid; i < 64 * (K / 2); i += 256) {
        int n = i / (K / 2), kp = i % (K / 2);
        *(uint32*)&Bl[n * KP + kp * 2] = Wtb[i];
    }
    int r0 = blockIdx.x * 64;
    const float* Xb = X + (size_t)r0 * K;
    int limit = (nrows - r0) * K;
    for (int f = tid * 4; f < 64 * K; f += 1024) {
        float4 v = {0.f, 0.f, 0.f, 0.f};
        if (f + 3 < limit) v = *(const float4*)&Xb[f];
        int row = f / K, kpos = f % K;
        ushort4 pk;
        pk.x = (unsigned short)f2bf(v.x);
        pk.y = (unsigned short)f2bf(v.y);
        pk.z = (unsigned short)f2bf(v.z);
        pk.w = (unsigned short)f2bf(v.w);
        *(ushort4*)&Al[row * KP + kpos] = pk;
    }
    __syncthreads();
    int lane = tid & 63, wv = tid >> 6;
    int m = lane & 15, quad = lane >> 4;
    f32x4 acc0 = {0.f, 0.f, 0.f, 0.f}, acc1 = acc0, acc2 = acc0, acc3 = acc0;
    int arow = wv * 16 + m;
#pragma unroll
    for (int k0 = 0; k0 < K; k0 += 32) {
        int koff = k0 + quad * 8;
        bf16x8 a = *(const bf16x8*)&Al[arow * KP + koff];
        bf16x8 b0 = *(const bf16x8*)&Bl[(0 * 16 + m) * KP + koff];
        bf16x8 b1 = *(const bf16x8*)&Bl[(1 * 16 + m) * KP + koff];
        bf16x8 b2 = *(const bf16x8*)&Bl[(2 * 16 + m) * KP + koff];
        bf16x8 b3 = *(const bf16x8*)&Bl[(3 * 16 + m) * KP + koff];
        acc0 = __builtin_amdgcn_mfma_f32_16x16x32_bf16(a, b0, acc0, 0, 0, 0);
        acc1 = __builtin_amdgcn_mfma_f32_16x16x32_bf16(a, b1, acc1, 0, 0, 0);
        acc2 = __builtin_amdgcn_mfma_f32_16x16x32_bf16(a, b2, acc2, 0, 0, 0);
        acc3 = __builtin_amdgcn_mfma_f32_16x16x32_bf16(a, b3, acc3, 0, 0, 0);
    }
    // C/D layout: col = nt*16 + m, row = quad*4 + reg.
    float dv[4];
#pragma unroll
    for (int reg = 0; reg < 4; ++reg) {
        int row = r0 + wv * 16 + quad * 4 + reg;
        dv[reg] = (row < nrows) ? dinv[row] : 0.f;
    }
    const float* accs[4] = {(const float*)&acc0, (const float*)&acc1,
                            (const float*)&acc2, (const float*)&acc3};
#pragma unroll
    for (int nt = 0; nt < 4; ++nt) {
#pragma unroll
        for (int reg = 0; reg < 4; ++reg) {
            float val = accs[nt][reg] * dv[reg];
            float nxt = __shfl_down(val, 1);
            int row = r0 + wv * 16 + quad * 4 + reg;
            if (((m & 1) == 0) && row < nrows)
                outb[(size_t)row * 32 + nt * 8 + (m >> 1)] =
                    f2bf(val) | (f2bf(nxt) << 16);
        }
    }
}

// ---------- fused GCN aggregate + selfloop + BN + ReLU (+resid), bf16 ------
// One wave per node; 32 lanes cover a 128B bf16 row, 2 wave halves = 2 edges
// per load, 16 edges / 8 loads in flight per step (R9 structure, known-good).
// R11: hwb rows PRE-SCALED by dinv[src] (GEMM epilogue) -> unweighted sum;
// only src indices are shuffled (8/chunk, was 16); adds not fmas; tail lanes
// point at zeroed row NN so every load/add is unconditional. No per-thread
// arrays (R10 lesson: PromoteAlloca moves them to LDS).
__global__ void k_gcn_gather(const uint32* __restrict__ hwb, const int* __restrict__ col,
                             const int* __restrict__ offs,
                             const float* __restrict__ dinv, const float* __restrict__ scale,
                             const float* __restrict__ shift, const float* __restrict__ resid,
                             float* __restrict__ out) {
    int node = blockIdx.x * 4 + (threadIdx.x >> 6);
    if (node >= NN) return;
    int lane = threadIdx.x & 63;
    int half = lane >> 5;
    int fl = lane & 31;                 // feature pair: {2fl, 2fl+1}
    int e0 = offs[node], e1 = offs[node + 1];
    float di = dinv[node];
    uint32 uself = hwb[(size_t)node * 32 + fl];   // independent of edge loop
    float ax0 = 0.f, ay0 = 0.f, ax1 = 0.f, ay1 = 0.f;
    for (int base = e0; base < e1; base += 64) {
        int m = e1 - base; if (m > 64) m = 64;
        int srcv = NN;                  // zero-row sentinel for tail lanes
        if (lane < m) srcv = col[base + lane];
        for (int j = 0; j < m; j += 16) {
            int s0 = __shfl(srcv, j + half);
            int s1 = __shfl(srcv, j + 2 + half);
            int s2 = __shfl(srcv, j + 4 + half);
            int s3 = __shfl(srcv, j + 6 + half);
            int s4 = __shfl(srcv, j + 8 + half);
            int s5 = __shfl(srcv, j + 10 + half);
            int s6 = __shfl(srcv, j + 12 + half);
            int s7 = __shfl(srcv, j + 14 + half);
            uint32 u0 = hwb[(size_t)s0 * 32 + fl];
            uint32 u1 = hwb[(size_t)s1 * 32 + fl];
            uint32 u2 = hwb[(size_t)s2 * 32 + fl];
            uint32 u3 = hwb[(size_t)s3 * 32 + fl];
            uint32 u4 = hwb[(size_t)s4 * 32 + fl];
            uint32 u5 = hwb[(size_t)s5 * 32 + fl];
            uint32 u6 = hwb[(size_t)s6 * 32 + fl];
            uint32 u7 = hwb[(size_t)s7 * 32 + fl];
            ax0 += bf_lo(u0); ay0 += bf_hi(u0);
            ax1 += bf_lo(u1); ay1 += bf_hi(u1);
            ax0 += bf_lo(u2); ay0 += bf_hi(u2);
            ax1 += bf_lo(u3); ay1 += bf_hi(u3);
            ax0 += bf_lo(u4); ay0 += bf_hi(u4);
            ax1 += bf_lo(u5); ay1 += bf_hi(u5);
            ax0 += bf_lo(u6); ay0 += bf_hi(u6);
            ax1 += bf_lo(u7); ay1 += bf_hi(u7);
        }
    }
    float ax = ax0 + ax1, ay = ay0 + ay1;
    ax += __shfl(ax, fl + 32);
    ay += __shfl(ay, fl + 32);
    if (half == 0) {
        // rows pre-scaled: out = (sum + self_scaled) * dinv[node], then BN.
        float vx = fmaf((ax + bf_lo(uself)) * di, scale[2 * fl],     shift[2 * fl]);
        float vy = fmaf((ay + bf_hi(uself)) * di, scale[2 * fl + 1], shift[2 * fl + 1]);
        vx = fmaxf(vx, 0.f);
        vy = fmaxf(vy, 0.f);
        if (resid) {
            float2 rv = *(const float2*)&resid[(size_t)node * 64 + 2 * fl];
            vx += rv.x; vy += rv.y;
        }
        float2 o; o.x = vx; o.y = vy;
        *(float2*)&out[(size_t)node * 64 + 2 * fl] = o;
    }
}

// ---------------- pooling over sorted batch, 4 waves x 32 nodes -----------
__global__ __launch_bounds__(256) void k_pool(const float* __restrict__ h,
                       const int* __restrict__ batch,
                       float* __restrict__ msum, float* __restrict__ mmax,
                       float* __restrict__ gcnt) {
    int lane = threadIdx.x & 63;
    int wv = threadIdx.x >> 6;
    int i0 = blockIdx.x * 128 + wv * 32;
    if (i0 >= NN) return;
    int i1 = i0 + 32; if (i1 > NN) i1 = NN;
    int cur = batch[i0];
    float sum = 0.f, mx = 0.f; int c = 0;
    for (int i = i0; i < i1; ++i) {
        int g = batch[i];
        if (g != cur) {
            atomicAdd(&msum[cur * 64 + lane], sum);
            atomicMax((unsigned int*)&mmax[cur * 64 + lane], __float_as_uint(mx));
            if (lane == 0) atomicAdd(&gcnt[cur], (float)c);
            sum = 0.f; mx = 0.f; c = 0; cur = g;
        }
        float v = h[(long)i * 64 + lane];
        sum += v; mx = fmaxf(mx, v); ++c;
    }
    atomicAdd(&msum[cur * 64 + lane], sum);
    atomicMax((unsigned int*)&mmax[cur * 64 + lane], __float_as_uint(mx));
    if (lane == 0) atomicAdd(&gcnt[cur], (float)c);
}

// ---------------- MLP head, one block per graph ----------------
__global__ void k_head(const float* __restrict__ msum, const float* __restrict__ mmax,
                       const float* __restrict__ gcnt,
                       const float* __restrict__ Wh1, const float* __restrict__ bh1,
                       const float* __restrict__ Wh2, const float* __restrict__ bh2,
                       const float* __restrict__ Wh3, const float* __restrict__ bh3,
                       float* __restrict__ out) {
    int g = blockIdx.x, t = threadIdx.x;  // 64 threads
    __shared__ float hg[128];
    __shared__ float z1[64];
    __shared__ float z2[32];
    float c = fmaxf(gcnt[g], 1.f);
    hg[t]      = msum[g * 64 + t] / c;
    hg[64 + t] = mmax[g * 64 + t];
    __syncthreads();
    float acc = bh1[t];
#pragma unroll 8
    for (int k = 0; k < 128; ++k) acc = fmaf(hg[k], Wh1[k * 64 + t], acc);
    z1[t] = fmaxf(acc, 0.f);
    __syncthreads();
    if (t < 32) {
        float a2 = bh2[t];
#pragma unroll 8
        for (int k = 0; k < 64; ++k) a2 = fmaf(z1[k], Wh2[k * 32 + t], a2);
        z2[t] = fmaxf(a2, 0.f);
    }
    __syncthreads();
    if (t == 0) {
        float a3 = bh3[0];
        for (int k = 0; k < 32; ++k) a3 = fmaf(z2[k], Wh3[k], a3);
        out[g] = 1.f / (1.f + expf(-a3));
    }
}

// ---------------- launcher ----------------

static inline size_t alignup(size_t x) { return (x + 255) & ~(size_t)255; }

extern "C" void kernel_launch(void* const* d_in, const int* in_sizes, int n_in,
                              void* d_out, int out_size, void* d_ws, size_t ws_size,
                              hipStream_t stream) {
    const float* x   = (const float*)d_in[0];
    const int*   ei  = (const int*)d_in[1];
    const int*   bat = (const int*)d_in[2];
    const float* W1  = (const float*)d_in[3];
    const float* b1  = (const float*)d_in[4];
    const float* g1  = (const float*)d_in[5];
    const float* be1 = (const float*)d_in[6];
    const float* rm1 = (const float*)d_in[7];
    const float* rv1 = (const float*)d_in[8];
    const float* W2  = (const float*)d_in[9];
    const float* b2  = (const float*)d_in[10];
    const float* g2  = (const float*)d_in[11];
    const float* be2 = (const float*)d_in[12];
    const float* rm2 = (const float*)d_in[13];
    const float* rv2 = (const float*)d_in[14];
    const float* Wh1 = (const float*)d_in[15];
    const float* bh1 = (const float*)d_in[16];
    const float* Wh2 = (const float*)d_in[17];
    const float* bh2 = (const float*)d_in[18];
    const float* Wh3 = (const float*)d_in[19];
    const float* bh3 = (const float*)d_in[20];
    float* out = (float*)d_out;

    char* ws = (char*)d_ws;
    size_t o = 0;
    int*   hblk   = (int*)(ws + o);  o = alignup(o + (size_t)P1_TILES * NBUK * 4);
    int*   rbase  = (int*)(ws + o);  o = alignup(o + (size_t)P1_TILES * NBUK * 4);
    int*   bbase  = (int*)(ws + o);  o = alignup(o + (NBUK + 1) * 4);
    int*   offs   = (int*)(ws + o);  o = alignup(o + (NN + 1) * 4);
    uint32* pairs = (uint32*)(ws + o); o = alignup(o + (size_t)EE * 4);
    int*   col    = (int*)(ws + o);  o = alignup(o + (size_t)EE * 4);
    float* dinv   = (float*)(ws + o); o = alignup(o + (size_t)NN * 4);
    float* scb    = (float*)(ws + o); o = alignup(o + 4 * 64 * 4);
    uint32* Wt1b  = (uint32*)(ws + o); o = alignup(o + 64 * (INF_ / 2) * 4);
    uint32* Wt2b  = (uint32*)(ws + o); o = alignup(o + 64 * (HID / 2) * 4);
    float* msum   = (float*)(ws + o); o += (size_t)GG * 64 * 4;
    float* mmax   = (float*)(ws + o); o += (size_t)GG * 64 * 4;
    float* gcnt   = (float*)(ws + o); o += (size_t)GG * 4;
    o = alignup(o);
    uint32* hwb   = (uint32*)(ws + o); o = alignup(o + (size_t)(NN + 1) * 32 * 4); // +1 zero row
    float* h      = (float*)(ws + o); o = alignup(o + (size_t)NN * 64 * 4);
    (void)ws_size; (void)n_in; (void)in_sizes; (void)out_size;

    // CSR build + setup + pool-zero (one kernel, 3 block roles)
    k_hist1<<<P1_TILES + SETUP_B + ZERO_B, 256, 0, stream>>>(
        ei, hblk, b1, g1, be1, rm1, rv1, b2, g2, be2, rm2, rv2, scb,
        W1, Wt1b, W2, Wt2b, msum);
    k_scan2<<<1, 512, 0, stream>>>(hblk, bbase, rbase, offs, hwb);
    k_p1b<<<P1_TILES, 256, 0, stream>>>(ei, rbase, pairs);
    k_p2<<<NBUK, 256, 0, stream>>>(pairs, bbase, offs, dinv, col);

    // layer 1 (GEMM epilogue pre-scales rows by dinv -> gather is a plain sum)
    k_gemm_mfma<INF_><<<(NN + 63) / 64, 256, 0, stream>>>(x, Wt1b, dinv, hwb, NN);
    k_gcn_gather<<<(NN + 3) / 4, 256, 0, stream>>>(hwb, col, offs, dinv,
                                                   scb, scb + 64, nullptr, h);
    // layer 2 (residual, in-place into h)
    k_gemm_mfma<HID><<<(NN + 63) / 64, 256, 0, stream>>>(h, Wt2b, dinv, hwb, NN);
    k_gcn_gather<<<(NN + 3) / 4, 256, 0, stream>>>(hwb, col, offs, dinv,
                                                   scb + 128, scb + 192, h, h);
    // pooling + head
    k_pool<<<(NN + 127) / 128, 256, 0, stream>>>(h, bat, msum, mmax, gcnt);
    k_head<<<GG, 64, 0, stream>>>(msum, mmax, gcnt, Wh1, bh1, Wh2, bh2, Wh3, bh3, out);
}

// Round 3
// 297.744 us; speedup vs baseline: 2.1502x; 1.0271x over previous
//
#include <hip/hip_runtime.h>
#include <math.h>

#define NN 100000
#define EE 1600000
#define GG 512
#define INF_ 128
#define HID 64
#define EPS 1e-5f

#define NBUK 391          // ceil(NN/256), bucket = dst >> 8
#define P1_TILES 98       // ceil((EE/4)/4096)
#define GB_B 25           // graph-boundary role blocks
#define GEMM1_B 1563      // ceil(NN/64)

typedef unsigned int uint32;
typedef __attribute__((ext_vector_type(8))) short bf16x8;
typedef __attribute__((ext_vector_type(4))) float f32x4;

// bf16 helpers: RNE pack, shift decode
static __device__ inline uint32 f2bf(float f) {
    uint32 u = __float_as_uint(f);
    return (u + 0x7FFFu + ((u >> 16) & 1u)) >> 16;
}
static __device__ inline float bf_lo(uint32 u) { return __uint_as_float(u << 16); }
static __device__ inline float bf_hi(uint32 u) { return __uint_as_float(u & 0xFFFF0000u); }

// History:
// R3: per-edge atomic scatter -> 12x cross-XCD write amp; bucketed 2-level sort.
// R9: single-histogram CSR build; 303us baseline.
// R10 FAILED: per-thread s[16] -> PromoteAlloca -> 64KB LDS, 38M bank conf.
// R11: hwb pre-scaled by dinv (gemm epilogue); gather 43.2us; total 305.8.
//      Lesson: gather is memory-system-bound (2.97 TB/s TCC-side, 50% L2 hit
//      on 12.8MB table vs 4MiB/XCD L2); instruction shaving exhausted.
// R12: non-gather time ~219us stable across rounds >> sum of kernel work
//      estimates (~80us) -> launch/drain overhead hypothesis (~10us x 10).
//      Fuse: [gemm1(unscaled,self-pack) || hist || graph-bounds] one launch;
//      BN-fold into scan2; pool+head -> one boundary-based kernel (no atomics).
//      gather1 reverts to verified R0 weighted form (dinv[src] shuffle).

// ---------------- shared GEMM body: [nrows,K]f32 @ W[K,64]f32 -> bf16 -----
// 64x64 tile/block, 4 waves x 4 n-tiles, 16x16x32 bf16 MFMA. Self-packs W
// (raw f32, coalesced row-pair reads; W is L2-hot across blocks).
// Rows padded +8 bf16: 256B-stride frag loads 16-way -> 2-way (free, m136).
template <int K, bool SCALE>
__device__ __forceinline__ void gemm_body(const float* __restrict__ X,
        const float* __restrict__ W, const float* __restrict__ dinv,
        uint32* __restrict__ outb, int nrows, int bx,
        unsigned short* __restrict__ Al, unsigned short* __restrict__ Bl) {
    constexpr int KP = K + 8;
    int tid = threadIdx.x;
    // pack W transposed: Bl[n*KP + 2kp] = pack(W[2kp][n], W[2kp+1][n]).
    // i&63 = n -> wave reads 64 consecutive floats of row 2kp: coalesced.
    for (int i = tid; i < 64 * (K / 2); i += 256) {
        int n = i & 63, kp = i >> 6;
        uint32 lo = f2bf(W[(size_t)(2 * kp) * 64 + n]);
        uint32 hi = f2bf(W[(size_t)(2 * kp + 1) * 64 + n]);
        *(uint32*)&Bl[n * KP + kp * 2] = lo | (hi << 16);
    }
    int r0 = bx * 64;
    const float* Xb = X + (size_t)r0 * K;
    int limit = (nrows - r0) * K;
    for (int f = tid * 4; f < 64 * K; f += 1024) {
        float4 v = {0.f, 0.f, 0.f, 0.f};
        if (f + 3 < limit) v = *(const float4*)&Xb[f];
        int row = f / K, kpos = f % K;
        ushort4 pk;
        pk.x = (unsigned short)f2bf(v.x);
        pk.y = (unsigned short)f2bf(v.y);
        pk.z = (unsigned short)f2bf(v.z);
        pk.w = (unsigned short)f2bf(v.w);
        *(ushort4*)&Al[row * KP + kpos] = pk;
    }
    __syncthreads();
    int lane = tid & 63, wv = tid >> 6;
    int m = lane & 15, quad = lane >> 4;
    f32x4 acc0 = {0.f, 0.f, 0.f, 0.f}, acc1 = acc0, acc2 = acc0, acc3 = acc0;
    int arow = wv * 16 + m;
#pragma unroll
    for (int k0 = 0; k0 < K; k0 += 32) {
        int koff = k0 + quad * 8;
        bf16x8 a = *(const bf16x8*)&Al[arow * KP + koff];
        bf16x8 b0 = *(const bf16x8*)&Bl[(0 * 16 + m) * KP + koff];
        bf16x8 b1 = *(const bf16x8*)&Bl[(1 * 16 + m) * KP + koff];
        bf16x8 b2 = *(const bf16x8*)&Bl[(2 * 16 + m) * KP + koff];
        bf16x8 b3 = *(const bf16x8*)&Bl[(3 * 16 + m) * KP + koff];
        acc0 = __builtin_amdgcn_mfma_f32_16x16x32_bf16(a, b0, acc0, 0, 0, 0);
        acc1 = __builtin_amdgcn_mfma_f32_16x16x32_bf16(a, b1, acc1, 0, 0, 0);
        acc2 = __builtin_amdgcn_mfma_f32_16x16x32_bf16(a, b2, acc2, 0, 0, 0);
        acc3 = __builtin_amdgcn_mfma_f32_16x16x32_bf16(a, b3, acc3, 0, 0, 0);
    }
    // C/D layout: col = nt*16 + m, row = quad*4 + reg.
    float dv[4];
#pragma unroll
    for (int reg = 0; reg < 4; ++reg) {
        int row = r0 + wv * 16 + quad * 4 + reg;
        if (SCALE) dv[reg] = (row < nrows) ? dinv[row] : 0.f;
        else       dv[reg] = 1.f;
    }
    const float* accs[4] = {(const float*)&acc0, (const float*)&acc1,
                            (const float*)&acc2, (const float*)&acc3};
#pragma unroll
    for (int nt = 0; nt < 4; ++nt) {
#pragma unroll
        for (int reg = 0; reg < 4; ++reg) {
            float val = accs[nt][reg] * dv[reg];
            float nxt = __shfl_down(val, 1);
            int row = r0 + wv * 16 + quad * 4 + reg;
            if (((m & 1) == 0) && row < nrows)
                outb[(size_t)row * 32 + nt * 8 + (m >> 1)] =
                    f2bf(val) | (f2bf(nxt) << 16);
        }
    }
}

// ---------------- mega front-end: hist | graph-bounds | gemm1 (unscaled) ---
// All three roles are mutually independent (hist: ei; gb: batch; gemm1: x,W1).
// Roles ordered hist/gb first so they co-schedule under the gemm wave.
__global__ __launch_bounds__(256) void k_mega(const int* __restrict__ ei,
        int* __restrict__ hblk, const int* __restrict__ bat, int* __restrict__ gb,
        const float* __restrict__ x, const float* __restrict__ W1,
        uint32* __restrict__ hwb) {
    __shared__ alignas(16) char smem[64 * (INF_ + 8) * 2 * 2];
    int b = blockIdx.x, t = threadIdx.x;
    if (b < P1_TILES) {
        int* h = (int*)smem;
        for (int i = t; i < NBUK; i += 256) h[i] = 0;
        __syncthreads();
        const int4* dst4 = (const int4*)(ei + EE);
        int base4 = b * 4096;
        for (int j = 0; j < 16; ++j) {
            int i4 = base4 + j * 256 + t;
            if (i4 < EE / 4) {
                int4 d = dst4[i4];
                atomicAdd(&h[d.x >> 8], 1);
                atomicAdd(&h[d.y >> 8], 1);
                atomicAdd(&h[d.z >> 8], 1);
                atomicAdd(&h[d.w >> 8], 1);
            }
        }
        __syncthreads();
        for (int i = t; i < NBUK; i += 256) hblk[b * NBUK + i] = h[i];
    } else if (b < P1_TILES + GB_B) {
        // gb[g] = first node index with batch >= g (batch sorted). gb[GG]=NN.
        int gid = (b - P1_TILES) * 256 + t;
        for (int i = gid; i < NN; i += GB_B * 256) {
            int bi = bat[i];
            if (i == 0) {
                for (int g = 0; g <= bi; ++g) gb[g] = 0;
            } else {
                int bp = bat[i - 1];
                for (int g = bp + 1; g <= bi; ++g) gb[g] = i;
            }
            if (i == NN - 1)
                for (int g = bi + 1; g <= GG; ++g) gb[g] = NN;
        }
    } else {
        int bx = b - P1_TILES - GB_B;
        unsigned short* Al = (unsigned short*)smem;
        unsigned short* Bl = (unsigned short*)(smem + 64 * (INF_ + 8) * 2);
        gemm_body<INF_, false>(x, W1, nullptr, hwb, NN, bx, Al, Bl);
    }
}

// one block, 512 threads: bucket totals, bucket scan -> bbase, per-block run
// bases -> rbase. Deterministic, no atomics. Extra roles: hwb zero row (tail
// sentinel), BN fold (threads 448..511).
__global__ void k_scan2(const int* __restrict__ hblk, int* __restrict__ bbase,
                        int* __restrict__ rbase, int* __restrict__ offs,
                        uint32* __restrict__ hwb,
                        const float* b1, const float* g1, const float* be1,
                        const float* rm1, const float* rv1,
                        const float* b2, const float* g2, const float* be2,
                        const float* rm2, const float* rv2, float* sc) {
    __shared__ int wsum[8];
    int t = threadIdx.x;  // 512
    int lane = t & 63, w = t >> 6;
    if (t < 32) hwb[(size_t)NN * 32 + t] = 0u;
    if (t >= 448) {
        int l = t - 448;
        float s1 = g1[l] * rsqrtf(rv1[l] + EPS);
        sc[l]       = s1;
        sc[64 + l]  = (b1[l] - rm1[l]) * s1 + be1[l];
        float s2 = g2[l] * rsqrtf(rv2[l] + EPS);
        sc[128 + l] = s2;
        sc[192 + l] = (b2[l] - rm2[l]) * s2 + be2[l];
    }
    int c = 0;
    if (t < NBUK)
        for (int b = 0; b < P1_TILES; ++b) c += hblk[b * NBUK + t];
    int v = c;
    for (int d = 1; d < 64; d <<= 1) { int n = __shfl_up(v, d); if (lane >= d) v += n; }
    if (lane == 63) wsum[w] = v;
    __syncthreads();
    int pre = 0;
    for (int q = 0; q < w; ++q) pre += wsum[q];
    int excl = pre + v - c;
    if (t <= NBUK) bbase[t] = excl;
    if (t == 0) offs[NN] = EE;
    if (t < NBUK) {
        int run = excl;
        for (int b = 0; b < P1_TILES; ++b) {
            rbase[b * NBUK + t] = run;
            run += hblk[b * NBUK + t];
        }
    }
}

// scatter packed (src<<8)|(dst&255) into CSR-ordered bucket regions
__global__ __launch_bounds__(256) void k_p1b(const int* __restrict__ ei,
                                             const int* __restrict__ rbase,
                                             uint32* __restrict__ pairs) {
    __shared__ int h[NBUK];
    int b = blockIdx.x, t = threadIdx.x;
    for (int i = t; i < NBUK; i += 256) h[i] = rbase[b * NBUK + i];
    __syncthreads();
    const int4* src4 = (const int4*)ei;
    const int4* dst4 = (const int4*)(ei + EE);
    int base4 = b * 4096;
    for (int j = 0; j < 16; ++j) {
        int i4 = base4 + j * 256 + t;
        if (i4 < EE / 4) {
            int4 d = dst4[i4];
            int4 s = src4[i4];
            int p0 = atomicAdd(&h[d.x >> 8], 1);
            pairs[p0] = ((uint32)s.x << 8) | (uint32)(d.x & 255);
            int p1 = atomicAdd(&h[d.y >> 8], 1);
            pairs[p1] = ((uint32)s.y << 8) | (uint32)(d.y & 255);
            int p2 = atomicAdd(&h[d.z >> 8], 1);
            pairs[p2] = ((uint32)s.z << 8) | (uint32)(d.z & 255);
            int p3 = atomicAdd(&h[d.w >> 8], 1);
            pairs[p3] = ((uint32)s.w << 8) | (uint32)(d.w & 255);
        }
    }
}

// per-bucket (256 nodes) CSR finalize in LDS: count, scan, scatter col
__global__ __launch_bounds__(256) void k_p2(const uint32* __restrict__ pairs,
                                            const int* __restrict__ bbase,
                                            int* __restrict__ offs, float* __restrict__ dinv,
                                            int* __restrict__ col) {
    int b = blockIdx.x, t = threadIdx.x;
    int nbase = b << 8;
    int ebase = bbase[b], eend = bbase[b + 1];
    int m = eend - ebase;
    __shared__ int cnt[256];
    __shared__ int wsum[4];
    cnt[t] = 0;
    __syncthreads();
    for (int i = t; i < m; i += 256)
        atomicAdd(&cnt[pairs[ebase + i] & 255u], 1);
    __syncthreads();
    int c = cnt[t];
    int lane = t & 63, w = t >> 6;
    int v = c;
    for (int d = 1; d < 64; d <<= 1) { int n = __shfl_up(v, d); if (lane >= d) v += n; }
    if (lane == 63) wsum[w] = v;
    __syncthreads();
    int pre = 0;
    for (int q = 0; q < w; ++q) pre += wsum[q];
    int excl = pre + v - c;
    int node = nbase + t;
    if (node < NN) {
        offs[node] = ebase + excl;
        dinv[node] = rsqrtf(1.f + (float)c);
    }
    __syncthreads();
    cnt[t] = excl;
    __syncthreads();
    for (int i = t; i < m; i += 256) {
        uint32 u = pairs[ebase + i];
        int loc = atomicAdd(&cnt[u & 255u], 1);
        col[ebase + loc] = (int)(u >> 8);
    }
}

// ---------- gather layer 1: WEIGHTED (hwb unscaled), verified R0 form ------
// One wave per node; 32 lanes cover a 128B bf16 row, 2 wave halves = 2 edges
// per load. dinv[src] loaded coalesced once per 64-edge chunk, shuffled.
// Tail lanes: srcv=NN (zeroed row), wv=0 -> unconditional loads/fmas.
__global__ void k_gcn_gather_w(const uint32* __restrict__ hwb, const int* __restrict__ col,
                               const int* __restrict__ offs,
                               const float* __restrict__ dinv, const float* __restrict__ scale,
                               const float* __restrict__ shift,
                               float* __restrict__ out) {
    int node = blockIdx.x * 4 + (threadIdx.x >> 6);
    if (node >= NN) return;
    int lane = threadIdx.x & 63;
    int half = lane >> 5;
    int fl = lane & 31;                 // feature pair: {2fl, 2fl+1}
    int e0 = offs[node], e1 = offs[node + 1];
    float di = dinv[node];
    uint32 uself = hwb[(size_t)node * 32 + fl];
    float ax0 = 0.f, ay0 = 0.f, ax1 = 0.f, ay1 = 0.f;
    for (int base = e0; base < e1; base += 64) {
        int m = e1 - base; if (m > 64) m = 64;
        int srcv = NN; float wv = 0.f;
        if (lane < m) { srcv = col[base + lane]; wv = dinv[srcv]; }
        for (int j = 0; j < m; j += 16) {
            int   s0 = __shfl(srcv, j + half);
            int   s1 = __shfl(srcv, j + 2 + half);
            int   s2 = __shfl(srcv, j + 4 + half);
            int   s3 = __shfl(srcv, j + 6 + half);
            int   s4 = __shfl(srcv, j + 8 + half);
            int   s5 = __shfl(srcv, j + 10 + half);
            int   s6 = __shfl(srcv, j + 12 + half);
            int   s7 = __shfl(srcv, j + 14 + half);
            float w0 = __shfl(wv, j + half);
            float w1 = __shfl(wv, j + 2 + half);
            float w2 = __shfl(wv, j + 4 + half);
            float w3 = __shfl(wv, j + 6 + half);
            float w4 = __shfl(wv, j + 8 + half);
            float w5 = __shfl(wv, j + 10 + half);
            float w6 = __shfl(wv, j + 12 + half);
            float w7 = __shfl(wv, j + 14 + half);
            uint32 u0 = hwb[(size_t)s0 * 32 + fl];
            uint32 u1 = hwb[(size_t)s1 * 32 + fl];
            uint32 u2 = hwb[(size_t)s2 * 32 + fl];
            uint32 u3 = hwb[(size_t)s3 * 32 + fl];
            uint32 u4 = hwb[(size_t)s4 * 32 + fl];
            uint32 u5 = hwb[(size_t)s5 * 32 + fl];
            uint32 u6 = hwb[(size_t)s6 * 32 + fl];
            uint32 u7 = hwb[(size_t)s7 * 32 + fl];
            ax0 = fmaf(bf_lo(u0), w0, ax0); ay0 = fmaf(bf_hi(u0), w0, ay0);
            ax1 = fmaf(bf_lo(u1), w1, ax1); ay1 = fmaf(bf_hi(u1), w1, ay1);
            ax0 = fmaf(bf_lo(u2), w2, ax0); ay0 = fmaf(bf_hi(u2), w2, ay0);
            ax1 = fmaf(bf_lo(u3), w3, ax1); ay1 = fmaf(bf_hi(u3), w3, ay1);
            ax0 = fmaf(bf_lo(u4), w4, ax0); ay0 = fmaf(bf_hi(u4), w4, ay0);
            ax1 = fmaf(bf_lo(u5), w5, ax1); ay1 = fmaf(bf_hi(u5), w5, ay1);
            ax0 = fmaf(bf_lo(u6), w6, ax0); ay0 = fmaf(bf_hi(u6), w6, ay0);
            ax1 = fmaf(bf_lo(u7), w7, ax1); ay1 = fmaf(bf_hi(u7), w7, ay1);
        }
    }
    float ax = ax0 + ax1, ay = ay0 + ay1;
    ax += __shfl(ax, fl + 32);
    ay += __shfl(ay, fl + 32);
    if (half == 0) {
        float dii = di * di;
        float vx = fmaf(ax * di + bf_lo(uself) * dii, scale[2 * fl],     shift[2 * fl]);
        float vy = fmaf(ay * di + bf_hi(uself) * dii, scale[2 * fl + 1], shift[2 * fl + 1]);
        vx = fmaxf(vx, 0.f);
        vy = fmaxf(vy, 0.f);
        float2 o; o.x = vx; o.y = vy;
        *(float2*)&out[(size_t)node * 64 + 2 * fl] = o;
    }
}

// ---------- gather layer 2: UNWEIGHTED (hwb pre-scaled), verified R11 ------
__global__ void k_gcn_gather(const uint32* __restrict__ hwb, const int* __restrict__ col,
                             const int* __restrict__ offs,
                             const float* __restrict__ dinv, const float* __restrict__ scale,
                             const float* __restrict__ shift, const float* __restrict__ resid,
                             float* __restrict__ out) {
    int node = blockIdx.x * 4 + (threadIdx.x >> 6);
    if (node >= NN) return;
    int lane = threadIdx.x & 63;
    int half = lane >> 5;
    int fl = lane & 31;                 // feature pair: {2fl, 2fl+1}
    int e0 = offs[node], e1 = offs[node + 1];
    float di = dinv[node];
    uint32 uself = hwb[(size_t)node * 32 + fl];
    float ax0 = 0.f, ay0 = 0.f, ax1 = 0.f, ay1 = 0.f;
    for (int base = e0; base < e1; base += 64) {
        int m = e1 - base; if (m > 64) m = 64;
        int srcv = NN;                  // zero-row sentinel for tail lanes
        if (lane < m) srcv = col[base + lane];
        for (int j = 0; j < m; j += 16) {
            int s0 = __shfl(srcv, j + half);
            int s1 = __shfl(srcv, j + 2 + half);
            int s2 = __shfl(srcv, j + 4 + half);
            int s3 = __shfl(srcv, j + 6 + half);
            int s4 = __shfl(srcv, j + 8 + half);
            int s5 = __shfl(srcv, j + 10 + half);
            int s6 = __shfl(srcv, j + 12 + half);
            int s7 = __shfl(srcv, j + 14 + half);
            uint32 u0 = hwb[(size_t)s0 * 32 + fl];
            uint32 u1 = hwb[(size_t)s1 * 32 + fl];
            uint32 u2 = hwb[(size_t)s2 * 32 + fl];
            uint32 u3 = hwb[(size_t)s3 * 32 + fl];
            uint32 u4 = hwb[(size_t)s4 * 32 + fl];
            uint32 u5 = hwb[(size_t)s5 * 32 + fl];
            uint32 u6 = hwb[(size_t)s6 * 32 + fl];
            uint32 u7 = hwb[(size_t)s7 * 32 + fl];
            ax0 += bf_lo(u0); ay0 += bf_hi(u0);
            ax1 += bf_lo(u1); ay1 += bf_hi(u1);
            ax0 += bf_lo(u2); ay0 += bf_hi(u2);
            ax1 += bf_lo(u3); ay1 += bf_hi(u3);
            ax0 += bf_lo(u4); ay0 += bf_hi(u4);
            ax1 += bf_lo(u5); ay1 += bf_hi(u5);
            ax0 += bf_lo(u6); ay0 += bf_hi(u6);
            ax1 += bf_lo(u7); ay1 += bf_hi(u7);
        }
    }
    float ax = ax0 + ax1, ay = ay0 + ay1;
    ax += __shfl(ax, fl + 32);
    ay += __shfl(ay, fl + 32);
    if (half == 0) {
        float vx = fmaf((ax + bf_lo(uself)) * di, scale[2 * fl],     shift[2 * fl]);
        float vy = fmaf((ay + bf_hi(uself)) * di, scale[2 * fl + 1], shift[2 * fl + 1]);
        vx = fmaxf(vx, 0.f);
        vy = fmaxf(vy, 0.f);
        if (resid) {
            float2 rv = *(const float2*)&resid[(size_t)node * 64 + 2 * fl];
            vx += rv.x; vy += rv.y;
        }
        float2 o; o.x = vx; o.y = vy;
        *(float2*)&out[(size_t)node * 64 + 2 * fl] = o;
    }
}

// ---------------- fused pooling + MLP head: one block per graph -----------
// gb[] gives each graph's contiguous node range (batch sorted). Register
// sum/max reduction (no atomics, no zero-init buffers), then verified MLP.
__global__ void k_poolhead(const float* __restrict__ h, const int* __restrict__ gb,
                           const float* __restrict__ Wh1, const float* __restrict__ bh1,
                           const float* __restrict__ Wh2, const float* __restrict__ bh2,
                           const float* __restrict__ Wh3, const float* __restrict__ bh3,
                           float* __restrict__ out) {
    int g = blockIdx.x, t = threadIdx.x;  // 64 threads
    int lo = gb[g], hi = gb[g + 1];
    float s0 = 0.f, s1 = 0.f, s2 = 0.f, s3 = 0.f;
    float s4 = 0.f, s5 = 0.f, s6 = 0.f, s7 = 0.f;
    float m0 = 0.f, m1 = 0.f, m2 = 0.f, m3 = 0.f;
    float m4 = 0.f, m5 = 0.f, m6 = 0.f, m7 = 0.f;   // h >= 0 (post-ReLU chain)
    int i = lo;
    for (; i + 8 <= hi; i += 8) {
        float v0 = h[(size_t)(i + 0) * 64 + t];
        float v1 = h[(size_t)(i + 1) * 64 + t];
        float v2 = h[(size_t)(i + 2) * 64 + t];
        float v3 = h[(size_t)(i + 3) * 64 + t];
        float v4 = h[(size_t)(i + 4) * 64 + t];
        float v5 = h[(size_t)(i + 5) * 64 + t];
        float v6 = h[(size_t)(i + 6) * 64 + t];
        float v7 = h[(size_t)(i + 7) * 64 + t];
        s0 += v0; m0 = fmaxf(m0, v0);
        s1 += v1; m1 = fmaxf(m1, v1);
        s2 += v2; m2 = fmaxf(m2, v2);
        s3 += v3; m3 = fmaxf(m3, v3);
        s4 += v4; m4 = fmaxf(m4, v4);
        s5 += v5; m5 = fmaxf(m5, v5);
        s6 += v6; m6 = fmaxf(m6, v6);
        s7 += v7; m7 = fmaxf(m7, v7);
    }
    for (; i < hi; ++i) {
        float v = h[(size_t)i * 64 + t];
        s0 += v; m0 = fmaxf(m0, v);
    }
    float sum = ((s0 + s1) + (s2 + s3)) + ((s4 + s5) + (s6 + s7));
    float mx = fmaxf(fmaxf(fmaxf(m0, m1), fmaxf(m2, m3)),
                     fmaxf(fmaxf(m4, m5), fmaxf(m6, m7)));
    float c = fmaxf((float)(hi - lo), 1.f);
    __shared__ float hg[128];
    __shared__ float z1[64];
    __shared__ float z2[32];
    hg[t]      = sum / c;
    hg[64 + t] = mx;
    __syncthreads();
    float acc = bh1[t];
#pragma unroll 8
    for (int k = 0; k < 128; ++k) acc = fmaf(hg[k], Wh1[k * 64 + t], acc);
    z1[t] = fmaxf(acc, 0.f);
    __syncthreads();
    if (t < 32) {
        float a2 = bh2[t];
#pragma unroll 8
        for (int k = 0; k < 64; ++k) a2 = fmaf(z1[k], Wh2[k * 32 + t], a2);
        z2[t] = fmaxf(a2, 0.f);
    }
    __syncthreads();
    if (t == 0) {
        float a3 = bh3[0];
        for (int k = 0; k < 32; ++k) a3 = fmaf(z2[k], Wh3[k], a3);
        out[g] = 1.f / (1.f + expf(-a3));
    }
}

// ---------------- standalone GEMM layer 2 (dinv-scaled epilogue) ----------
__global__ __launch_bounds__(256) void k_gemm2(const float* __restrict__ X,
                                               const float* __restrict__ W,
                                               const float* __restrict__ dinv,
                                               uint32* __restrict__ outb) {
    __shared__ alignas(16) unsigned short Al[64 * (HID + 8)];
    __shared__ alignas(16) unsigned short Bl[64 * (HID + 8)];
    gemm_body<HID, true>(X, W, dinv, outb, NN, blockIdx.x, Al, Bl);
}

// ---------------- launcher ----------------

static inline size_t alignup(size_t x) { return (x + 255) & ~(size_t)255; }

extern "C" void kernel_launch(void* const* d_in, const int* in_sizes, int n_in,
                              void* d_out, int out_size, void* d_ws, size_t ws_size,
                              hipStream_t stream) {
    const float* x   = (const float*)d_in[0];
    const int*   ei  = (const int*)d_in[1];
    const int*   bat = (const int*)d_in[2];
    const float* W1  = (const float*)d_in[3];
    const float* b1  = (const float*)d_in[4];
    const float* g1  = (const float*)d_in[5];
    const float* be1 = (const float*)d_in[6];
    const float* rm1 = (const float*)d_in[7];
    const float* rv1 = (const float*)d_in[8];
    const float* W2  = (const float*)d_in[9];
    const float* b2  = (const float*)d_in[10];
    const float* g2  = (const float*)d_in[11];
    const float* be2 = (const float*)d_in[12];
    const float* rm2 = (const float*)d_in[13];
    const float* rv2 = (const float*)d_in[14];
    const float* Wh1 = (const float*)d_in[15];
    const float* bh1 = (const float*)d_in[16];
    const float* Wh2 = (const float*)d_in[17];
    const float* bh2 = (const float*)d_in[18];
    const float* Wh3 = (const float*)d_in[19];
    const float* bh3 = (const float*)d_in[20];
    float* out = (float*)d_out;

    char* ws = (char*)d_ws;
    size_t o = 0;
    int*   hblk   = (int*)(ws + o);  o = alignup(o + (size_t)P1_TILES * NBUK * 4);
    int*   rbase  = (int*)(ws + o);  o = alignup(o + (size_t)P1_TILES * NBUK * 4);
    int*   bbase  = (int*)(ws + o);  o = alignup(o + (NBUK + 1) * 4);
    int*   offs   = (int*)(ws + o);  o = alignup(o + (NN + 1) * 4);
    uint32* pairs = (uint32*)(ws + o); o = alignup(o + (size_t)EE * 4);
    int*   col    = (int*)(ws + o);  o = alignup(o + (size_t)EE * 4);
    float* dinv   = (float*)(ws + o); o = alignup(o + (size_t)NN * 4);
    float* scb    = (float*)(ws + o); o = alignup(o + 4 * 64 * 4);
    int*   gb     = (int*)(ws + o);  o = alignup(o + (GG + 1) * 4);
    uint32* hwb   = (uint32*)(ws + o); o = alignup(o + (size_t)(NN + 1) * 32 * 4); // +1 zero row
    float* h      = (float*)(ws + o); o = alignup(o + (size_t)NN * 64 * 4);
    (void)ws_size; (void)n_in; (void)in_sizes; (void)out_size;

    // 1. front-end: hist || graph-bounds || gemm1 (unscaled, self-pack)
    k_mega<<<P1_TILES + GB_B + GEMM1_B, 256, 0, stream>>>(ei, hblk, bat, gb,
                                                          x, W1, hwb);
    // 2. scan + BN-fold + hwb zero-row
    k_scan2<<<1, 512, 0, stream>>>(hblk, bbase, rbase, offs, hwb,
                                   b1, g1, be1, rm1, rv1, b2, g2, be2, rm2, rv2, scb);
    // 3-4. CSR finalize
    k_p1b<<<P1_TILES, 256, 0, stream>>>(ei, rbase, pairs);
    k_p2<<<NBUK, 256, 0, stream>>>(pairs, bbase, offs, dinv, col);

    // 5. layer-1 gather (weighted: hwb rows unscaled)
    k_gcn_gather_w<<<(NN + 3) / 4, 256, 0, stream>>>(hwb, col, offs, dinv,
                                                     scb, scb + 64, h);
    // 6. layer-2 GEMM (epilogue pre-scales rows by dinv)
    k_gemm2<<<GEMM1_B, 256, 0, stream>>>(h, W2, dinv, hwb);
    // 7. layer-2 gather (unweighted, residual)
    k_gcn_gather<<<(NN + 3) / 4, 256, 0, stream>>>(hwb, col, offs, dinv,
                                                   scb + 128, scb + 192, h, h);
    // 8. fused pooling + head
    k_poolhead<<<GG, 64, 0, stream>>>(h, gb, Wh1, bh1, Wh2, bh2, Wh3, bh3, out);
}

// Round 4
// 285.892 us; speedup vs baseline: 2.2393x; 1.0415x over previous
//
#include <hip/hip_runtime.h>
#include <math.h>

#define NN 100000
#define EE 1600000
#define GG 512
#define INF_ 128
#define HID 64
#define EPS 1e-5f

#define NBUK 391          // ceil(NN/256), bucket = dst >> 8
#define P1_TILES 98       // ceil((EE/4)/4096)
#define GB_B 25           // graph-boundary role blocks
#define GEMM1_B 1563      // ceil(NN/64)

typedef unsigned int uint32;
typedef __attribute__((ext_vector_type(8))) short bf16x8;
typedef __attribute__((ext_vector_type(4))) float f32x4;
typedef __attribute__((ext_vector_type(2))) float f32x2;

// bf16 helpers: RNE pack, shift decode
static __device__ inline uint32 f2bf(float f) {
    uint32 u = __float_as_uint(f);
    return (u + 0x7FFFu + ((u >> 16) & 1u)) >> 16;
}

// History:
// R3: per-edge atomic scatter -> 12x cross-XCD write amp; bucketed 2-level sort.
// R9: single-histogram CSR build; 303us baseline.
// R10 FAILED: per-thread s[16] -> PromoteAlloca -> 64KB LDS, 38M bank conf.
// R11: gather is memory-bound: instruction shaving (-30% VALU) bought only 5%.
// R12: launch fusion 10->8; total 297.7. FETCH = table x 8 XCDs exactly ->
//      gather sits at the compulsory per-XCD L2-fill floor at 2.97 TB/s
//      (L3->L2 fill ceiling). Only lever left: shrink the table.
// R13: hwb in fp8-e4m3 (64B rows). Table 12.8->6.4MB, fetch floor 102->51MB,
//      1 line/row. Gather lanes: quarter=lane>>4 (4 edges/round), fl=lane&15
//      (4 features/lane), v_cvt_pk_f32_fp8 decode, quarter-reduce shfl_xor.

// ---------------- shared GEMM body: [nrows,K]f32 @ W[K,64]f32 -> fp8 ------
// 64x64 tile/block, 4 waves x 4 n-tiles, 16x16x32 bf16 MFMA. Self-packs W
// (raw f32, coalesced row-pair reads; W is L2-hot across blocks).
// Rows padded +8 bf16: 256B-stride frag loads 16-way -> 2-way (free, m136).
// Epilogue: 4 cols packed per uint32 via v_cvt_pk_fp8_f32; optional dinv scale.
template <int K, bool SCALE>
__device__ __forceinline__ void gemm_body(const float* __restrict__ X,
        const float* __restrict__ W, const float* __restrict__ dinv,
        uint32* __restrict__ outb, int nrows, int bx,
        unsigned short* __restrict__ Al, unsigned short* __restrict__ Bl) {
    constexpr int KP = K + 8;
    int tid = threadIdx.x;
    // pack W transposed: Bl[n*KP + 2kp] = pack(W[2kp][n], W[2kp+1][n]).
    for (int i = tid; i < 64 * (K / 2); i += 256) {
        int n = i & 63, kp = i >> 6;
        uint32 lo = f2bf(W[(size_t)(2 * kp) * 64 + n]);
        uint32 hi = f2bf(W[(size_t)(2 * kp + 1) * 64 + n]);
        *(uint32*)&Bl[n * KP + kp * 2] = lo | (hi << 16);
    }
    int r0 = bx * 64;
    const float* Xb = X + (size_t)r0 * K;
    int limit = (nrows - r0) * K;
    for (int f = tid * 4; f < 64 * K; f += 1024) {
        float4 v = {0.f, 0.f, 0.f, 0.f};
        if (f + 3 < limit) v = *(const float4*)&Xb[f];
        int row = f / K, kpos = f % K;
        ushort4 pk;
        pk.x = (unsigned short)f2bf(v.x);
        pk.y = (unsigned short)f2bf(v.y);
        pk.z = (unsigned short)f2bf(v.z);
        pk.w = (unsigned short)f2bf(v.w);
        *(ushort4*)&Al[row * KP + kpos] = pk;
    }
    __syncthreads();
    int lane = tid & 63, wv = tid >> 6;
    int m = lane & 15, quad = lane >> 4;
    f32x4 acc0 = {0.f, 0.f, 0.f, 0.f}, acc1 = acc0, acc2 = acc0, acc3 = acc0;
    int arow = wv * 16 + m;
#pragma unroll
    for (int k0 = 0; k0 < K; k0 += 32) {
        int koff = k0 + quad * 8;
        bf16x8 a = *(const bf16x8*)&Al[arow * KP + koff];
        bf16x8 b0 = *(const bf16x8*)&Bl[(0 * 16 + m) * KP + koff];
        bf16x8 b1 = *(const bf16x8*)&Bl[(1 * 16 + m) * KP + koff];
        bf16x8 b2 = *(const bf16x8*)&Bl[(2 * 16 + m) * KP + koff];
        bf16x8 b3 = *(const bf16x8*)&Bl[(3 * 16 + m) * KP + koff];
        acc0 = __builtin_amdgcn_mfma_f32_16x16x32_bf16(a, b0, acc0, 0, 0, 0);
        acc1 = __builtin_amdgcn_mfma_f32_16x16x32_bf16(a, b1, acc1, 0, 0, 0);
        acc2 = __builtin_amdgcn_mfma_f32_16x16x32_bf16(a, b2, acc2, 0, 0, 0);
        acc3 = __builtin_amdgcn_mfma_f32_16x16x32_bf16(a, b3, acc3, 0, 0, 0);
    }
    // C/D layout: col = nt*16 + m, row = quad*4 + reg.
    float dv[4];
#pragma unroll
    for (int reg = 0; reg < 4; ++reg) {
        int row = r0 + wv * 16 + quad * 4 + reg;
        if (SCALE) dv[reg] = (row < nrows) ? dinv[row] : 0.f;
        else       dv[reg] = 1.f;
    }
    const float* accs[4] = {(const float*)&acc0, (const float*)&acc1,
                            (const float*)&acc2, (const float*)&acc3};
#pragma unroll
    for (int nt = 0; nt < 4; ++nt) {
#pragma unroll
        for (int reg = 0; reg < 4; ++reg) {
            float val = accs[nt][reg] * dv[reg];
            float v1 = __shfl_down(val, 1);
            float v2 = __shfl_down(val, 2);
            float v3 = __shfl_down(val, 3);
            int row = r0 + wv * 16 + quad * 4 + reg;
            if (((m & 3) == 0) && row < nrows) {
                int u = __builtin_amdgcn_cvt_pk_fp8_f32(val, v1, 0, false);
                u = __builtin_amdgcn_cvt_pk_fp8_f32(v2, v3, u, true);
                outb[(size_t)row * 16 + nt * 4 + (m >> 2)] = (uint32)u;
            }
        }
    }
}

// ---------------- mega front-end: hist | graph-bounds | gemm1 (unscaled) ---
__global__ __launch_bounds__(256) void k_mega(const int* __restrict__ ei,
        int* __restrict__ hblk, const int* __restrict__ bat, int* __restrict__ gb,
        const float* __restrict__ x, const float* __restrict__ W1,
        uint32* __restrict__ hwb) {
    __shared__ alignas(16) char smem[64 * (INF_ + 8) * 2 * 2];
    int b = blockIdx.x, t = threadIdx.x;
    if (b < P1_TILES) {
        int* h = (int*)smem;
        for (int i = t; i < NBUK; i += 256) h[i] = 0;
        __syncthreads();
        const int4* dst4 = (const int4*)(ei + EE);
        int base4 = b * 4096;
        for (int j = 0; j < 16; ++j) {
            int i4 = base4 + j * 256 + t;
            if (i4 < EE / 4) {
                int4 d = dst4[i4];
                atomicAdd(&h[d.x >> 8], 1);
                atomicAdd(&h[d.y >> 8], 1);
                atomicAdd(&h[d.z >> 8], 1);
                atomicAdd(&h[d.w >> 8], 1);
            }
        }
        __syncthreads();
        for (int i = t; i < NBUK; i += 256) hblk[b * NBUK + i] = h[i];
    } else if (b < P1_TILES + GB_B) {
        // gb[g] = first node index with batch >= g (batch sorted). gb[GG]=NN.
        int gid = (b - P1_TILES) * 256 + t;
        for (int i = gid; i < NN; i += GB_B * 256) {
            int bi = bat[i];
            if (i == 0) {
                for (int g = 0; g <= bi; ++g) gb[g] = 0;
            } else {
                int bp = bat[i - 1];
                for (int g = bp + 1; g <= bi; ++g) gb[g] = i;
            }
            if (i == NN - 1)
                for (int g = bi + 1; g <= GG; ++g) gb[g] = NN;
        }
    } else {
        int bx = b - P1_TILES - GB_B;
        unsigned short* Al = (unsigned short*)smem;
        unsigned short* Bl = (unsigned short*)(smem + 64 * (INF_ + 8) * 2);
        gemm_body<INF_, false>(x, W1, nullptr, hwb, NN, bx, Al, Bl);
    }
}

// one block, 512 threads: bucket totals, bucket scan -> bbase, per-block run
// bases -> rbase. Extra roles: hwb zero row (tail sentinel), BN fold.
__global__ void k_scan2(const int* __restrict__ hblk, int* __restrict__ bbase,
                        int* __restrict__ rbase, int* __restrict__ offs,
                        uint32* __restrict__ hwb,
                        const float* b1, const float* g1, const float* be1,
                        const float* rm1, const float* rv1,
                        const float* b2, const float* g2, const float* be2,
                        const float* rm2, const float* rv2, float* sc) {
    __shared__ int wsum[8];
    int t = threadIdx.x;  // 512
    int lane = t & 63, w = t >> 6;
    if (t < 16) hwb[(size_t)NN * 16 + t] = 0u;
    if (t >= 448) {
        int l = t - 448;
        float s1 = g1[l] * rsqrtf(rv1[l] + EPS);
        sc[l]       = s1;
        sc[64 + l]  = (b1[l] - rm1[l]) * s1 + be1[l];
        float s2 = g2[l] * rsqrtf(rv2[l] + EPS);
        sc[128 + l] = s2;
        sc[192 + l] = (b2[l] - rm2[l]) * s2 + be2[l];
    }
    int c = 0;
    if (t < NBUK)
        for (int b = 0; b < P1_TILES; ++b) c += hblk[b * NBUK + t];
    int v = c;
    for (int d = 1; d < 64; d <<= 1) { int n = __shfl_up(v, d); if (lane >= d) v += n; }
    if (lane == 63) wsum[w] = v;
    __syncthreads();
    int pre = 0;
    for (int q = 0; q < w; ++q) pre += wsum[q];
    int excl = pre + v - c;
    if (t <= NBUK) bbase[t] = excl;
    if (t == 0) offs[NN] = EE;
    if (t < NBUK) {
        int run = excl;
        for (int b = 0; b < P1_TILES; ++b) {
            rbase[b * NBUK + t] = run;
            run += hblk[b * NBUK + t];
        }
    }
}

// scatter packed (src<<8)|(dst&255) into CSR-ordered bucket regions
__global__ __launch_bounds__(256) void k_p1b(const int* __restrict__ ei,
                                             const int* __restrict__ rbase,
                                             uint32* __restrict__ pairs) {
    __shared__ int h[NBUK];
    int b = blockIdx.x, t = threadIdx.x;
    for (int i = t; i < NBUK; i += 256) h[i] = rbase[b * NBUK + i];
    __syncthreads();
    const int4* src4 = (const int4*)ei;
    const int4* dst4 = (const int4*)(ei + EE);
    int base4 = b * 4096;
    for (int j = 0; j < 16; ++j) {
        int i4 = base4 + j * 256 + t;
        if (i4 < EE / 4) {
            int4 d = dst4[i4];
            int4 s = src4[i4];
            int p0 = atomicAdd(&h[d.x >> 8], 1);
            pairs[p0] = ((uint32)s.x << 8) | (uint32)(d.x & 255);
            int p1 = atomicAdd(&h[d.y >> 8], 1);
            pairs[p1] = ((uint32)s.y << 8) | (uint32)(d.y & 255);
            int p2 = atomicAdd(&h[d.z >> 8], 1);
            pairs[p2] = ((uint32)s.z << 8) | (uint32)(d.z & 255);
            int p3 = atomicAdd(&h[d.w >> 8], 1);
            pairs[p3] = ((uint32)s.w << 8) | (uint32)(d.w & 255);
        }
    }
}

// per-bucket (256 nodes) CSR finalize in LDS: count, scan, scatter col
__global__ __launch_bounds__(256) void k_p2(const uint32* __restrict__ pairs,
                                            const int* __restrict__ bbase,
                                            int* __restrict__ offs, float* __restrict__ dinv,
                                            int* __restrict__ col) {
    int b = blockIdx.x, t = threadIdx.x;
    int nbase = b << 8;
    int ebase = bbase[b], eend = bbase[b + 1];
    int m = eend - ebase;
    __shared__ int cnt[256];
    __shared__ int wsum[4];
    cnt[t] = 0;
    __syncthreads();
    for (int i = t; i < m; i += 256)
        atomicAdd(&cnt[pairs[ebase + i] & 255u], 1);
    __syncthreads();
    int c = cnt[t];
    int lane = t & 63, w = t >> 6;
    int v = c;
    for (int d = 1; d < 64; d <<= 1) { int n = __shfl_up(v, d); if (lane >= d) v += n; }
    if (lane == 63) wsum[w] = v;
    __syncthreads();
    int pre = 0;
    for (int q = 0; q < w; ++q) pre += wsum[q];
    int excl = pre + v - c;
    int node = nbase + t;
    if (node < NN) {
        offs[node] = ebase + excl;
        dinv[node] = rsqrtf(1.f + (float)c);
    }
    __syncthreads();
    cnt[t] = excl;
    __syncthreads();
    for (int i = t; i < m; i += 256) {
        uint32 u = pairs[ebase + i];
        int loc = atomicAdd(&cnt[u & 255u], 1);
        col[ebase + loc] = (int)(u >> 8);
    }
}

// ---------- gather layer 1: WEIGHTED (hwb unscaled fp8), one wave/node -----
// Lane = (quarter=lane>>4, fl=lane&15): 16 lanes cover a 64B fp8 row (4
// features/lane), 4 quarters = 4 edges per load round, 16 edges per j-block.
// Tail lanes: srcv=NN (zeroed row), wv=0. Quarter-reduce via shfl_xor 16/32.
__global__ void k_gcn_gather_w(const uint32* __restrict__ hwb, const int* __restrict__ col,
                               const int* __restrict__ offs,
                               const float* __restrict__ dinv, const float* __restrict__ scale,
                               const float* __restrict__ shift,
                               float* __restrict__ out) {
    int node = blockIdx.x * 4 + (threadIdx.x >> 6);
    if (node >= NN) return;
    int lane = threadIdx.x & 63;
    int quarter = lane >> 4;
    int fl = lane & 15;                 // features 4fl .. 4fl+3
    int e0 = offs[node], e1 = offs[node + 1];
    float di = dinv[node];
    uint32 uself = hwb[(size_t)node * 16 + fl];
    float a0 = 0.f, a1 = 0.f, a2 = 0.f, a3 = 0.f;
    float b0 = 0.f, b1 = 0.f, b2 = 0.f, b3 = 0.f;
    for (int base = e0; base < e1; base += 64) {
        int m = e1 - base; if (m > 64) m = 64;
        int srcv = NN; float wv = 0.f;
        if (lane < m) { srcv = col[base + lane]; wv = dinv[srcv]; }
        for (int j = 0; j < m; j += 16) {
            int   s0 = __shfl(srcv, j + quarter);
            int   s1 = __shfl(srcv, j + 4 + quarter);
            int   s2 = __shfl(srcv, j + 8 + quarter);
            int   s3 = __shfl(srcv, j + 12 + quarter);
            float w0 = __shfl(wv, j + quarter);
            float w1 = __shfl(wv, j + 4 + quarter);
            float w2 = __shfl(wv, j + 8 + quarter);
            float w3 = __shfl(wv, j + 12 + quarter);
            uint32 u0 = hwb[(size_t)s0 * 16 + fl];
            uint32 u1 = hwb[(size_t)s1 * 16 + fl];
            uint32 u2 = hwb[(size_t)s2 * 16 + fl];
            uint32 u3 = hwb[(size_t)s3 * 16 + fl];
            f32x2 l0 = __builtin_amdgcn_cvt_pk_f32_fp8((int)u0, false);
            f32x2 h0 = __builtin_amdgcn_cvt_pk_f32_fp8((int)u0, true);
            f32x2 l1 = __builtin_amdgcn_cvt_pk_f32_fp8((int)u1, false);
            f32x2 h1 = __builtin_amdgcn_cvt_pk_f32_fp8((int)u1, true);
            f32x2 l2 = __builtin_amdgcn_cvt_pk_f32_fp8((int)u2, false);
            f32x2 h2 = __builtin_amdgcn_cvt_pk_f32_fp8((int)u2, true);
            f32x2 l3 = __builtin_amdgcn_cvt_pk_f32_fp8((int)u3, false);
            f32x2 h3 = __builtin_amdgcn_cvt_pk_f32_fp8((int)u3, true);
            a0 = fmaf(l0[0], w0, a0); a1 = fmaf(l0[1], w0, a1);
            a2 = fmaf(h0[0], w0, a2); a3 = fmaf(h0[1], w0, a3);
            b0 = fmaf(l1[0], w1, b0); b1 = fmaf(l1[1], w1, b1);
            b2 = fmaf(h1[0], w1, b2); b3 = fmaf(h1[1], w1, b3);
            a0 = fmaf(l2[0], w2, a0); a1 = fmaf(l2[1], w2, a1);
            a2 = fmaf(h2[0], w2, a2); a3 = fmaf(h2[1], w2, a3);
            b0 = fmaf(l3[0], w3, b0); b1 = fmaf(l3[1], w3, b1);
            b2 = fmaf(h3[0], w3, b2); b3 = fmaf(h3[1], w3, b3);
        }
    }
    a0 += b0; a1 += b1; a2 += b2; a3 += b3;
    a0 += __shfl_xor(a0, 16); a0 += __shfl_xor(a0, 32);
    a1 += __shfl_xor(a1, 16); a1 += __shfl_xor(a1, 32);
    a2 += __shfl_xor(a2, 16); a2 += __shfl_xor(a2, 32);
    a3 += __shfl_xor(a3, 16); a3 += __shfl_xor(a3, 32);
    if (quarter == 0) {
        f32x2 slo = __builtin_amdgcn_cvt_pk_f32_fp8((int)uself, false);
        f32x2 shi = __builtin_amdgcn_cvt_pk_f32_fp8((int)uself, true);
        float dii = di * di;
        float4 sc4 = *(const float4*)&scale[4 * fl];
        float4 sh4 = *(const float4*)&shift[4 * fl];
        float v0 = fmaf(a0 * di + slo[0] * dii, sc4.x, sh4.x);
        float v1 = fmaf(a1 * di + slo[1] * dii, sc4.y, sh4.y);
        float v2 = fmaf(a2 * di + shi[0] * dii, sc4.z, sh4.z);
        float v3 = fmaf(a3 * di + shi[1] * dii, sc4.w, sh4.w);
        float4 o;
        o.x = fmaxf(v0, 0.f); o.y = fmaxf(v1, 0.f);
        o.z = fmaxf(v2, 0.f); o.w = fmaxf(v3, 0.f);
        *(float4*)&out[(size_t)node * 64 + 4 * fl] = o;
    }
}

// ---------- gather layer 2: UNWEIGHTED (hwb pre-scaled fp8), residual ------
__global__ void k_gcn_gather(const uint32* __restrict__ hwb, const int* __restrict__ col,
                             const int* __restrict__ offs,
                             const float* __restrict__ dinv, const float* __restrict__ scale,
                             const float* __restrict__ shift, const float* __restrict__ resid,
                             float* __restrict__ out) {
    int node = blockIdx.x * 4 + (threadIdx.x >> 6);
    if (node >= NN) return;
    int lane = threadIdx.x & 63;
    int quarter = lane >> 4;
    int fl = lane & 15;                 // features 4fl .. 4fl+3
    int e0 = offs[node], e1 = offs[node + 1];
    float di = dinv[node];
    uint32 uself = hwb[(size_t)node * 16 + fl];
    float a0 = 0.f, a1 = 0.f, a2 = 0.f, a3 = 0.f;
    float b0 = 0.f, b1 = 0.f, b2 = 0.f, b3 = 0.f;
    for (int base = e0; base < e1; base += 64) {
        int m = e1 - base; if (m > 64) m = 64;
        int srcv = NN;                  // zero-row sentinel for tail lanes
        if (lane < m) srcv = col[base + lane];
        for (int j = 0; j < m; j += 16) {
            int s0 = __shfl(srcv, j + quarter);
            int s1 = __shfl(srcv, j + 4 + quarter);
            int s2 = __shfl(srcv, j + 8 + quarter);
            int s3 = __shfl(srcv, j + 12 + quarter);
            uint32 u0 = hwb[(size_t)s0 * 16 + fl];
            uint32 u1 = hwb[(size_t)s1 * 16 + fl];
            uint32 u2 = hwb[(size_t)s2 * 16 + fl];
            uint32 u3 = hwb[(size_t)s3 * 16 + fl];
            f32x2 l0 = __builtin_amdgcn_cvt_pk_f32_fp8((int)u0, false);
            f32x2 h0 = __builtin_amdgcn_cvt_pk_f32_fp8((int)u0, true);
            f32x2 l1 = __builtin_amdgcn_cvt_pk_f32_fp8((int)u1, false);
            f32x2 h1 = __builtin_amdgcn_cvt_pk_f32_fp8((int)u1, true);
            f32x2 l2 = __builtin_amdgcn_cvt_pk_f32_fp8((int)u2, false);
            f32x2 h2 = __builtin_amdgcn_cvt_pk_f32_fp8((int)u2, true);
            f32x2 l3 = __builtin_amdgcn_cvt_pk_f32_fp8((int)u3, false);
            f32x2 h3 = __builtin_amdgcn_cvt_pk_f32_fp8((int)u3, true);
            a0 += l0[0]; a1 += l0[1]; a2 += h0[0]; a3 += h0[1];
            b0 += l1[0]; b1 += l1[1]; b2 += h1[0]; b3 += h1[1];
            a0 += l2[0]; a1 += l2[1]; a2 += h2[0]; a3 += h2[1];
            b0 += l3[0]; b1 += l3[1]; b2 += h3[0]; b3 += h3[1];
        }
    }
    a0 += b0; a1 += b1; a2 += b2; a3 += b3;
    a0 += __shfl_xor(a0, 16); a0 += __shfl_xor(a0, 32);
    a1 += __shfl_xor(a1, 16); a1 += __shfl_xor(a1, 32);
    a2 += __shfl_xor(a2, 16); a2 += __shfl_xor(a2, 32);
    a3 += __shfl_xor(a3, 16); a3 += __shfl_xor(a3, 32);
    if (quarter == 0) {
        f32x2 slo = __builtin_amdgcn_cvt_pk_f32_fp8((int)uself, false);
        f32x2 shi = __builtin_amdgcn_cvt_pk_f32_fp8((int)uself, true);
        float4 sc4 = *(const float4*)&scale[4 * fl];
        float4 sh4 = *(const float4*)&shift[4 * fl];
        float v0 = fmaf((a0 + slo[0]) * di, sc4.x, sh4.x);
        float v1 = fmaf((a1 + slo[1]) * di, sc4.y, sh4.y);
        float v2 = fmaf((a2 + shi[0]) * di, sc4.z, sh4.z);
        float v3 = fmaf((a3 + shi[1]) * di, sc4.w, sh4.w);
        float4 rv = *(const float4*)&resid[(size_t)node * 64 + 4 * fl];
        float4 o;
        o.x = fmaxf(v0, 0.f) + rv.x;
        o.y = fmaxf(v1, 0.f) + rv.y;
        o.z = fmaxf(v2, 0.f) + rv.z;
        o.w = fmaxf(v3, 0.f) + rv.w;
        *(float4*)&out[(size_t)node * 64 + 4 * fl] = o;
    }
}

// ---------------- fused pooling + MLP head: one block per graph -----------
__global__ void k_poolhead(const float* __restrict__ h, const int* __restrict__ gb,
                           const float* __restrict__ Wh1, const float* __restrict__ bh1,
                           const float* __restrict__ Wh2, const float* __restrict__ bh2,
                           const float* __restrict__ Wh3, const float* __restrict__ bh3,
                           float* __restrict__ out) {
    int g = blockIdx.x, t = threadIdx.x;  // 64 threads
    int lo = gb[g], hi = gb[g + 1];
    float s0 = 0.f, s1 = 0.f, s2 = 0.f, s3 = 0.f;
    float s4 = 0.f, s5 = 0.f, s6 = 0.f, s7 = 0.f;
    float m0 = 0.f, m1 = 0.f, m2 = 0.f, m3 = 0.f;
    float m4 = 0.f, m5 = 0.f, m6 = 0.f, m7 = 0.f;   // h >= 0 (post-ReLU chain)
    int i = lo;
    for (; i + 8 <= hi; i += 8) {
        float v0 = h[(size_t)(i + 0) * 64 + t];
        float v1 = h[(size_t)(i + 1) * 64 + t];
        float v2 = h[(size_t)(i + 2) * 64 + t];
        float v3 = h[(size_t)(i + 3) * 64 + t];
        float v4 = h[(size_t)(i + 4) * 64 + t];
        float v5 = h[(size_t)(i + 5) * 64 + t];
        float v6 = h[(size_t)(i + 6) * 64 + t];
        float v7 = h[(size_t)(i + 7) * 64 + t];
        s0 += v0; m0 = fmaxf(m0, v0);
        s1 += v1; m1 = fmaxf(m1, v1);
        s2 += v2; m2 = fmaxf(m2, v2);
        s3 += v3; m3 = fmaxf(m3, v3);
        s4 += v4; m4 = fmaxf(m4, v4);
        s5 += v5; m5 = fmaxf(m5, v5);
        s6 += v6; m6 = fmaxf(m6, v6);
        s7 += v7; m7 = fmaxf(m7, v7);
    }
    for (; i < hi; ++i) {
        float v = h[(size_t)i * 64 + t];
        s0 += v; m0 = fmaxf(m0, v);
    }
    float sum = ((s0 + s1) + (s2 + s3)) + ((s4 + s5) + (s6 + s7));
    float mx = fmaxf(fmaxf(fmaxf(m0, m1), fmaxf(m2, m3)),
                     fmaxf(fmaxf(m4, m5), fmaxf(m6, m7)));
    float c = fmaxf((float)(hi - lo), 1.f);
    __shared__ float hg[128];
    __shared__ float z1[64];
    __shared__ float z2[32];
    hg[t]      = sum / c;
    hg[64 + t] = mx;
    __syncthreads();
    float acc = bh1[t];
#pragma unroll 8
    for (int k = 0; k < 128; ++k) acc = fmaf(hg[k], Wh1[k * 64 + t], acc);
    z1[t] = fmaxf(acc, 0.f);
    __syncthreads();
    if (t < 32) {
        float a2 = bh2[t];
#pragma unroll 8
        for (int k = 0; k < 64; ++k) a2 = fmaf(z1[k], Wh2[k * 32 + t], a2);
        z2[t] = fmaxf(a2, 0.f);
    }
    __syncthreads();
    if (t == 0) {
        float a3 = bh3[0];
        for (int k = 0; k < 32; ++k) a3 = fmaf(z2[k], Wh3[k], a3);
        out[g] = 1.f / (1.f + expf(-a3));
    }
}

// ---------------- standalone GEMM layer 2 (dinv-scaled epilogue) ----------
__global__ __launch_bounds__(256) void k_gemm2(const float* __restrict__ X,
                                               const float* __restrict__ W,
                                               const float* __restrict__ dinv,
                                               uint32* __restrict__ outb) {
    __shared__ alignas(16) unsigned short Al[64 * (HID + 8)];
    __shared__ alignas(16) unsigned short Bl[64 * (HID + 8)];
    gemm_body<HID, true>(X, W, dinv, outb, NN, blockIdx.x, Al, Bl);
}

// ---------------- launcher ----------------

static inline size_t alignup(size_t x) { return (x + 255) & ~(size_t)255; }

extern "C" void kernel_launch(void* const* d_in, const int* in_sizes, int n_in,
                              void* d_out, int out_size, void* d_ws, size_t ws_size,
                              hipStream_t stream) {
    const float* x   = (const float*)d_in[0];
    const int*   ei  = (const int*)d_in[1];
    const int*   bat = (const int*)d_in[2];
    const float* W1  = (const float*)d_in[3];
    const float* b1  = (const float*)d_in[4];
    const float* g1  = (const float*)d_in[5];
    const float* be1 = (const float*)d_in[6];
    const float* rm1 = (const float*)d_in[7];
    const float* rv1 = (const float*)d_in[8];
    const float* W2  = (const float*)d_in[9];
    const float* b2  = (const float*)d_in[10];
    const float* g2  = (const float*)d_in[11];
    const float* be2 = (const float*)d_in[12];
    const float* rm2 = (const float*)d_in[13];
    const float* rv2 = (const float*)d_in[14];
    const float* Wh1 = (const float*)d_in[15];
    const float* bh1 = (const float*)d_in[16];
    const float* Wh2 = (const float*)d_in[17];
    const float* bh2 = (const float*)d_in[18];
    const float* Wh3 = (const float*)d_in[19];
    const float* bh3 = (const float*)d_in[20];
    float* out = (float*)d_out;

    char* ws = (char*)d_ws;
    size_t o = 0;
    int*   hblk   = (int*)(ws + o);  o = alignup(o + (size_t)P1_TILES * NBUK * 4);
    int*   rbase  = (int*)(ws + o);  o = alignup(o + (size_t)P1_TILES * NBUK * 4);
    int*   bbase  = (int*)(ws + o);  o = alignup(o + (NBUK + 1) * 4);
    int*   offs   = (int*)(ws + o);  o = alignup(o + (NN + 1) * 4);
    uint32* pairs = (uint32*)(ws + o); o = alignup(o + (size_t)EE * 4);
    int*   col    = (int*)(ws + o);  o = alignup(o + (size_t)EE * 4);
    float* dinv   = (float*)(ws + o); o = alignup(o + (size_t)NN * 4);
    float* scb    = (float*)(ws + o); o = alignup(o + 4 * 64 * 4);
    int*   gb     = (int*)(ws + o);  o = alignup(o + (GG + 1) * 4);
    uint32* hwb   = (uint32*)(ws + o); o = alignup(o + (size_t)(NN + 1) * 16 * 4); // fp8 rows, +1 zero row
    float* h      = (float*)(ws + o); o = alignup(o + (size_t)NN * 64 * 4);
    (void)ws_size; (void)n_in; (void)in_sizes; (void)out_size;

    // 1. front-end: hist || graph-bounds || gemm1 (unscaled fp8, self-pack)
    k_mega<<<P1_TILES + GB_B + GEMM1_B, 256, 0, stream>>>(ei, hblk, bat, gb,
                                                          x, W1, hwb);
    // 2. scan + BN-fold + hwb zero-row
    k_scan2<<<1, 512, 0, stream>>>(hblk, bbase, rbase, offs, hwb,
                                   b1, g1, be1, rm1, rv1, b2, g2, be2, rm2, rv2, scb);
    // 3-4. CSR finalize
    k_p1b<<<P1_TILES, 256, 0, stream>>>(ei, rbase, pairs);
    k_p2<<<NBUK, 256, 0, stream>>>(pairs, bbase, offs, dinv, col);

    // 5. layer-1 gather (weighted: hwb rows unscaled)
    k_gcn_gather_w<<<(NN + 3) / 4, 256, 0, stream>>>(hwb, col, offs, dinv,
                                                     scb, scb + 64, h);
    // 6. layer-2 GEMM (epilogue pre-scales rows by dinv)
    k_gemm2<<<GEMM1_B, 256, 0, stream>>>(h, W2, dinv, hwb);
    // 7. layer-2 gather (unweighted, residual)
    k_gcn_gather<<<(NN + 3) / 4, 256, 0, stream>>>(hwb, col, offs, dinv,
                                                   scb + 128, scb + 192, h, h);
    // 8. fused pooling + head
    k_poolhead<<<GG, 64, 0, stream>>>(h, gb, Wh1, bh1, Wh2, bh2, Wh3, bh3, out);
}